// Round 1
// baseline (520.642 us; speedup 1.0000x reference)
//
#include <hip/hip_runtime.h>
#include <hip/hip_bf16.h>
#include <stdint.h>

#define D_IN 256
#define NEG 0.2f
#define LOG2E 1.44269504f

typedef unsigned short bf16_t;
typedef __attribute__((ext_vector_type(8))) short bfrag;   // 8 bf16 = 4 VGPR
typedef __attribute__((ext_vector_type(4))) float ffrag;   // MFMA C/D

__device__ __forceinline__ bf16_t f2bf(float f) {
  unsigned int u = __float_as_uint(f);
  unsigned int r = u + 0x7FFFu + ((u >> 16) & 1u);   // RNE
  return (bf16_t)(r >> 16);
}
__device__ __forceinline__ unsigned int pk2(float a, float b) {
  return (unsigned int)f2bf(a) | ((unsigned int)f2bf(b) << 16);
}
__device__ __forceinline__ void ld8bf(const bf16_t* p, float* f) {
  uint4 u = *(const uint4*)p;
  f[0] = __uint_as_float(u.x << 16);
  f[1] = __uint_as_float(u.x & 0xFFFF0000u);
  f[2] = __uint_as_float(u.y << 16);
  f[3] = __uint_as_float(u.y & 0xFFFF0000u);
  f[4] = __uint_as_float(u.z << 16);
  f[5] = __uint_as_float(u.z & 0xFFFF0000u);
  f[6] = __uint_as_float(u.w << 16);
  f[7] = __uint_as_float(u.w & 0xFFFF0000u);
}

// ---------------- K0: zero deg  UNION  Wt transpose+convert ----------------
__global__ __launch_bounds__(256) void k_zero_wt(int* __restrict__ deg, int n, int zb,
                                                 const float* __restrict__ Wl,
                                                 const float* __restrict__ Wr,
                                                 bf16_t* __restrict__ Wt) {
  const int b = blockIdx.x, tid = threadIdx.x;
  if (b < zb) {
    int i = b * 256 + tid;
    if (i < n) deg[i] = 0;
  } else {
    int gid = (b - zb) * 256 + tid;   // 2*256*256 total
    int w = gid >> 16;
    int c = (gid >> 8) & 255;
    int k = gid & 255;
    const float* W = w ? Wr : Wl;
    Wt[gid] = f2bf(W[k * 256 + c]);
  }
}

// ---------------- K_A: hist(+rank)  UNION  emb fp32->bf16 conv ----------------
__global__ __launch_bounds__(256) void k_hist_conv(const int* __restrict__ dst, int E,
                                                   int* __restrict__ deg, int* __restrict__ rank,
                                                   int hb,
                                                   const float* __restrict__ emb,
                                                   bf16_t* __restrict__ embh, int n4) {
  const int b = blockIdx.x, tid = threadIdx.x;
  if (b < hb) {
    int e = b * 256 + tid;
    if (e < E) rank[e] = atomicAdd(&deg[dst[e]], 1);
  } else {
    int i = (b - hb) * 256 + tid;
    if (i < n4) {
      float4 f = ((const float4*)emb)[i];
      uint2 o;
      o.x = pk2(f.x, f.y);
      o.y = pk2(f.z, f.w);
      ((uint2*)embh)[i] = o;
    }
  }
}

// ---------------- scan chain ----------------
__global__ __launch_bounds__(256) void k_scanA(const int* __restrict__ deg,
                                               int* __restrict__ offs,
                                               int* __restrict__ bsum, int N) {
  __shared__ int sh[256];
  int t = threadIdx.x;
  int base = blockIdx.x * 1024 + t * 4;
  int v[4];
#pragma unroll
  for (int q = 0; q < 4; q++) v[q] = (base + q < N) ? deg[base + q] : 0;
  int ls = v[0] + v[1] + v[2] + v[3];
  sh[t] = ls;
  __syncthreads();
  for (int ofs = 1; ofs < 256; ofs <<= 1) {
    int x = (t >= ofs) ? sh[t - ofs] : 0;
    __syncthreads();
    sh[t] += x;
    __syncthreads();
  }
  int run = sh[t] - ls;
#pragma unroll
  for (int q = 0; q < 4; q++) {
    if (base + q < N) offs[base + q] = run;
    run += v[q];
  }
  if (t == 255) bsum[blockIdx.x] = sh[255];
}

__global__ __launch_bounds__(128) void k_scanB(int* __restrict__ bsum, int* __restrict__ offs,
                                               int nb, int E, int N) {
  __shared__ int sh[128];
  int t = threadIdx.x;
  int v = (t < nb) ? bsum[t] : 0;
  sh[t] = v;
  __syncthreads();
  for (int ofs = 1; ofs < 128; ofs <<= 1) {
    int x = (t >= ofs) ? sh[t - ofs] : 0;
    __syncthreads();
    sh[t] += x;
    __syncthreads();
  }
  if (t < nb) bsum[t] = sh[t] - v;
  if (t == 0) offs[N] = E;
}

__global__ __launch_bounds__(256) void k_scanC(int* __restrict__ offs,
                                               const int* __restrict__ bsum, int N) {
  int t = threadIdx.x;
  int base = blockIdx.x * 1024 + t * 4;
  int add = bsum[blockIdx.x];
#pragma unroll
  for (int q = 0; q < 4; q++) {
    int i = base + q;
    if (i < N) offs[i] += add;
  }
}

// ---------------- K_E: MFMA GEMM  UNION  scatter (no atomic) ----------------
// gemm: 128x128 tile, BK=32, 4 waves x (64x64 via 4x4 MFMA 16x16x32)
// Epilogue: per-row head-dot bl = a . xl  (16-lane shuffle reduce) -> blr;
// stores |a_c|-scaled bf16 (k_edge unscales at the end).
// XCD swizzle: co-locate the 4 sibling blocks (same A row-tile) on one XCD.
template <bool USEBF>
__global__ __launch_bounds__(256) void k_gemm_scatter(
    const float* __restrict__ emb, const bf16_t* __restrict__ embh,
    const bf16_t* __restrict__ Wt, bf16_t* __restrict__ xl, bf16_t* __restrict__ xr,
    const int* __restrict__ src, const int* __restrict__ dst,
    const int* __restrict__ offs, const int* __restrict__ rank, int* __restrict__ csr,
    const float* __restrict__ att, float* __restrict__ blr,
    int N, int E, int gb) {
  __shared__ bf16_t As[128][40];
  __shared__ bf16_t Bs[128][40];
  const int tid = threadIdx.x;

  if ((int)blockIdx.x >= gb) {   // -------- scatter branch --------
    int e = ((int)blockIdx.x - gb) * 256 + tid;
    if (e < E) {
      int pos = offs[dst[e]] + rank[e];
      csr[pos] = src[e];
    }
    return;
  }

  // -------- gemm branch: bijective chunked XCD swizzle (8 XCDs) --------
  int g = (int)blockIdx.x;
  {
    int xcd = g & 7, slot = g >> 3;
    int q8 = gb >> 3, r8 = gb & 7;
    g = (xcd < r8 ? xcd * (q8 + 1) : r8 * (q8 + 1) + (xcd - r8) * q8) + slot;
  }
  const int bx = g >> 2, nt = g & 3;  // nt: 0,1->Wl; 2,3->Wr
  const int row0 = bx * 128;
  const bf16_t* Wp = Wt + (size_t)(nt >> 1) * 65536;
  bf16_t* dstp = (nt < 2) ? xl : xr;
  const int c0 = (nt & 1) * 128;

  const int wave = tid >> 6, lane = tid & 63;
  const int m0w = (wave & 1) * 64, n0w = (wave >> 1) * 64;
  const int fr = lane & 15;
  const int aq = (lane >> 4) * 8;

  const int srow = tid >> 1, sseg = (tid & 1) * 16;
  const int grow = row0 + srow;
  const bool aok = grow < N;
  const bf16_t* bp = Wp + (size_t)(c0 + srow) * 256 + sseg;

  ffrag acc[4][4];
#pragma unroll
  for (int mi = 0; mi < 4; mi++)
#pragma unroll
    for (int ni = 0; ni < 4; ni++) acc[mi][ni] = (ffrag)0.f;

  for (int k0 = 0; k0 < 256; k0 += 32) {
    uint4 pa0 = make_uint4(0, 0, 0, 0), pa1 = pa0;
    if (USEBF) {
      const bf16_t* ap = embh + (size_t)grow * 256 + sseg;
      if (aok) {
        pa0 = *(const uint4*)(ap + k0);
        pa1 = *(const uint4*)(ap + k0 + 8);
      }
    } else {
      const float* ap = emb + (size_t)grow * 256 + sseg;
      float4 f0 = make_float4(0, 0, 0, 0), f1 = f0, f2 = f0, f3 = f0;
      if (aok) {
        f0 = *(const float4*)(ap + k0);
        f1 = *(const float4*)(ap + k0 + 4);
        f2 = *(const float4*)(ap + k0 + 8);
        f3 = *(const float4*)(ap + k0 + 12);
      }
      pa0.x = pk2(f0.x, f0.y); pa0.y = pk2(f0.z, f0.w);
      pa0.z = pk2(f1.x, f1.y); pa0.w = pk2(f1.z, f1.w);
      pa1.x = pk2(f2.x, f2.y); pa1.y = pk2(f2.z, f2.w);
      pa1.z = pk2(f3.x, f3.y); pa1.w = pk2(f3.z, f3.w);
    }
    uint4 b0 = *(const uint4*)(bp + k0);
    uint4 b1 = *(const uint4*)(bp + k0 + 8);
    __syncthreads();
    *(uint4*)&As[srow][sseg] = pa0;
    *(uint4*)&As[srow][sseg + 8] = pa1;
    *(uint4*)&Bs[srow][sseg] = b0;
    *(uint4*)&Bs[srow][sseg + 8] = b1;
    __syncthreads();

    bfrag af[4], bfv[4];
#pragma unroll
    for (int mi = 0; mi < 4; mi++) af[mi] = *(const bfrag*)&As[m0w + mi * 16 + fr][aq];
#pragma unroll
    for (int ni = 0; ni < 4; ni++) bfv[ni] = *(const bfrag*)&Bs[n0w + ni * 16 + fr][aq];
#pragma unroll
    for (int mi = 0; mi < 4; mi++)
#pragma unroll
      for (int ni = 0; ni < 4; ni++)
        acc[mi][ni] = __builtin_amdgcn_mfma_f32_16x16x32_bf16(af[mi], bfv[ni], acc[mi][ni], 0, 0, 0);
  }

  const int rbase = m0w + (lane >> 4) * 4;

  // ---- per-row head-dot bl = sum_c a_c * x_c over this wave's 64 cols (one head) ----
  const int head = (c0 + n0w) >> 6;
  float aa[4], absa[4];
#pragma unroll
  for (int ni = 0; ni < 4; ni++) {
    aa[ni] = att[c0 + n0w + ni * 16 + fr];
    absa[ni] = fabsf(aa[ni]);
  }
#pragma unroll
  for (int mi = 0; mi < 4; mi++) {
#pragma unroll
    for (int rr = 0; rr < 4; rr++) {
      float p = aa[0] * acc[mi][0][rr];
      p = fmaf(aa[1], acc[mi][1][rr], p);
      p = fmaf(aa[2], acc[mi][2][rr], p);
      p = fmaf(aa[3], acc[mi][3][rr], p);
      p += __shfl_xor(p, 1);
      p += __shfl_xor(p, 2);
      p += __shfl_xor(p, 4);
      p += __shfl_xor(p, 8);
      int row = row0 + rbase + mi * 16 + rr;
      if (fr == 0 && row < N) blr[(size_t)row * 8 + (nt >> 1) * 4 + head] = p;
    }
  }

  // ---- scaled bf16 store: ail/air = |a_c| * x_c ----
#pragma unroll
  for (int mi = 0; mi < 4; mi++) {
#pragma unroll
    for (int ni = 0; ni < 4; ni++) {
      int col = c0 + n0w + ni * 16 + fr;
#pragma unroll
      for (int rr = 0; rr < 4; rr++) {
        int row = row0 + rbase + mi * 16 + rr;
        if (row < N) dstp[(size_t)row * 256 + col] = f2bf(acc[mi][ni][rr] * absa[ni]);
      }
    }
  }
}

// ---------------- fused edge pass (R5 layout) ----------------
// leaky decomposition: score = 0.6*(bl[j]+br[i]) + 0.4 * sum_c sgn_c*|ail_c + air_c|
//   with ail=|a|*xl, air=|a|*xr (bf16), bl/br precomputed in gemm epilogue (fp32).
// wave = 2 edge slots x 32 lanes; lane = (half<<5)|(head<<3)|chgrp, 8 ch/lane.
// exp folded to exp2 (log2e baked into C4/C6). |s|max ~ 1.1 -> overflow-safe.
__device__ __forceinline__ float red8(float p) {
  p += __shfl_xor(p, 1);
  p += __shfl_xor(p, 2);
  p += __shfl_xor(p, 4);
  return p;
}

__global__ __launch_bounds__(256) void k_edge(const bf16_t* __restrict__ ail,
                                              const bf16_t* __restrict__ air,
                                              const float* __restrict__ blr,
                                              const int* __restrict__ offs,
                                              const int* __restrict__ csr,
                                              const float* __restrict__ att,
                                              const float* __restrict__ bias,
                                              float* __restrict__ out, int N) {
  const int wv = threadIdx.x >> 6;
  const int lane = threadIdx.x & 63;
  const int i = blockIdx.x * 4 + wv;
  if (i >= N) return;
  const int half = lane >> 5;
  const int r = lane & 31;
  const int head = r >> 3;
  const int cbase = head * 64 + (r & 7) * 8;
  const float C4 = 0.4f * LOG2E, C6 = 0.6f * LOG2E;

  float sgn[8];
  {
    float4 a0 = *(const float4*)(att + cbase);
    float4 a1 = *(const float4*)(att + cbase + 4);
    sgn[0] = copysignf(1.f, a0.x); sgn[1] = copysignf(1.f, a0.y);
    sgn[2] = copysignf(1.f, a0.z); sgn[3] = copysignf(1.f, a0.w);
    sgn[4] = copysignf(1.f, a1.x); sgn[5] = copysignf(1.f, a1.y);
    sgn[6] = copysignf(1.f, a1.z); sgn[7] = copysignf(1.f, a1.w);
  }
  float airv[8];
  ld8bf(air + (size_t)i * 256 + cbase, airv);
  const float pre_i = C6 * blr[(size_t)i * 8 + 4 + head];  // 0.6*log2e * br[i]

  float d = 0.f;
  float acc[8] = {0.f, 0.f, 0.f, 0.f, 0.f, 0.f, 0.f, 0.f};

  // self loop on half 1 (half 0 gets the (possibly) larger edge share)
  if (half == 1) {
    float x[8];
    ld8bf(ail + (size_t)i * 256 + cbase, x);
    float p = 0.f;
#pragma unroll
    for (int q = 0; q < 8; q++) p = fmaf(sgn[q], fabsf(x[q] + airv[q]), p);
    p = red8(p);
    float e = exp2f(fmaf(C4, p, fmaf(C6, blr[(size_t)i * 8 + head], pre_i)));
    d = e;
#pragma unroll
    for (int q = 0; q < 8; q++) acc[q] = e * x[q];
  }

  // contiguous split: half0 = [k0, kmid), half1 = [kmid, kend)
  const int k0 = offs[i];
  const int kend = offs[i + 1];
  const int kmid = k0 + ((kend - k0 + 1) >> 1);
  int k = half ? kmid : k0;
  const int ke = half ? kend : kmid;

  for (; k + 1 < ke; k += 2) {
    int j0 = csr[k], j1 = csr[k + 1];
    float x0[8], x1[8];
    ld8bf(ail + (size_t)j0 * 256 + cbase, x0);
    ld8bf(ail + (size_t)j1 * 256 + cbase, x1);
    float bl0 = blr[(size_t)j0 * 8 + head];
    float bl1 = blr[(size_t)j1 * 8 + head];
    float p0 = 0.f, p1 = 0.f;
#pragma unroll
    for (int q = 0; q < 8; q++) {
      p0 = fmaf(sgn[q], fabsf(x0[q] + airv[q]), p0);
      p1 = fmaf(sgn[q], fabsf(x1[q] + airv[q]), p1);
    }
    p0 = red8(p0);
    p1 = red8(p1);
    float e0 = exp2f(fmaf(C4, p0, fmaf(C6, bl0, pre_i)));
    float e1 = exp2f(fmaf(C4, p1, fmaf(C6, bl1, pre_i)));
    d += e0 + e1;
#pragma unroll
    for (int q = 0; q < 8; q++) acc[q] += fmaf(e0, x0[q], e1 * x1[q]);
  }
  if (k < ke) {
    int j = csr[k];
    float x[8];
    ld8bf(ail + (size_t)j * 256 + cbase, x);
    float p = 0.f;
#pragma unroll
    for (int q = 0; q < 8; q++) p = fmaf(sgn[q], fabsf(x[q] + airv[q]), p);
    p = red8(p);
    float e = exp2f(fmaf(C4, p, fmaf(C6, blr[(size_t)j * 8 + head], pre_i)));
    d += e;
#pragma unroll
    for (int q = 0; q < 8; q++) acc[q] = fmaf(e, x[q], acc[q]);
  }

  // combine the two edge subsets (same head/channels in lanes l and l^32)
  d += __shfl_xor(d, 32);
#pragma unroll
  for (int q = 0; q < 8; q++) acc[q] += __shfl_xor(acc[q], 32);

  // per-head normalize + unscale by 1/|a_c|, then head-mean (xor 8, 16)
  float invd = 0.25f / d;
  float v[8];
  {
    float4 a0 = *(const float4*)(att + cbase);
    float4 a1 = *(const float4*)(att + cbase + 4);
    float inva[8] = {1.f / fabsf(a0.x), 1.f / fabsf(a0.y), 1.f / fabsf(a0.z), 1.f / fabsf(a0.w),
                     1.f / fabsf(a1.x), 1.f / fabsf(a1.y), 1.f / fabsf(a1.z), 1.f / fabsf(a1.w)};
#pragma unroll
    for (int q = 0; q < 8; q++) v[q] = acc[q] * invd * inva[q];
  }
#pragma unroll
  for (int q = 0; q < 8; q++) {
    v[q] += __shfl_xor(v[q], 8);
    v[q] += __shfl_xor(v[q], 16);
  }
  if ((lane >> 3) == 0) {  // half==0 && head==0 -> lanes 0..7 own 8 ch each
    const int cg = lane & 7;
    const float4 b0 = *(const float4*)(bias + cg * 8);
    const float4 b1 = *(const float4*)(bias + cg * 8 + 4);
    const float bb[8] = {b0.x, b0.y, b0.z, b0.w, b1.x, b1.y, b1.z, b1.w};
    float o[8];
#pragma unroll
    for (int q = 0; q < 8; q++) {
      float x = v[q] + bb[q];
      o[q] = x > 0.f ? x : (__expf(x) - 1.f);  // elu
    }
    *(float4*)(out + (size_t)i * 64 + cg * 8) = make_float4(o[0], o[1], o[2], o[3]);
    *(float4*)(out + (size_t)i * 64 + cg * 8 + 4) = make_float4(o[4], o[5], o[6], o[7]);
  }
}

extern "C" void kernel_launch(void* const* d_in, const int* in_sizes, int n_in,
                              void* d_out, int out_size, void* d_ws, size_t ws_size,
                              hipStream_t stream) {
  const int* edge = (const int*)d_in[1];   // [2][E] : row0 = src, row1 = dst
  const float* emb = (const float*)d_in[2];
  const float* Wl = (const float*)d_in[3];
  const float* Wr = (const float*)d_in[4];
  const float* att = (const float*)d_in[5];
  const float* bias = (const float*)d_in[6];
  float* out = (float*)d_out;

  const int E = in_sizes[1] / 2;
  const int N = in_sizes[2] / D_IN;
  const int* src = edge;
  const int* dst = edge + E;

  // strictly disjoint carve; embh (gated) at the end
  const size_t NB = (size_t)N * 256 * 2;
  char* w = (char*)d_ws;
  bf16_t* xl = (bf16_t*)w;  w += NB;            // ail = |a|*xl (bf16)
  bf16_t* xr = (bf16_t*)w;  w += NB;            // air = |a|*xr (bf16)
  bf16_t* Wt = (bf16_t*)w;  w += (size_t)2 * 256 * 256 * 2;
  int* offs = (int*)w;      w += ((size_t)N + 64) * 4;
  int* deg = (int*)w;       w += ((size_t)N + 64) * 4;
  int* bsum = (int*)w;      w += 1024;
  int* rank = (int*)w;      w += (size_t)E * 4;
  int* csr = (int*)w;       w += (size_t)E * 4;
  float* blr = (float*)w;   w += (size_t)N * 8 * 4;  // [N][8]: bl heads 0-3, br heads 0-3
  bf16_t* embh = (bf16_t*)w;
  const size_t need_big = (size_t)(w - (char*)d_ws) + NB;
  const bool big = ws_size >= need_big;   // ws_size constant -> same path every call

  const int nb = (N + 1023) / 1024;
  const int zb = (N + 255) / 256;
  const int hb = (E + 255) / 256;
  const int n4 = big ? N * 64 : 0;            // conv work items /4
  const int cb = big ? (n4 + 255) / 256 : 0;  // conv blocks
  const int gb = ((N + 127) / 128) * 4;       // gemm blocks
  const int sb = hb;                          // scatter blocks

  // K0: zero deg  U  Wt convert
  hipLaunchKernelGGL(k_zero_wt, dim3(zb + 512), dim3(256), 0, stream, deg, N, zb, Wl, Wr, Wt);
  // K_A: hist(+rank)  U  emb->bf16 conv
  hipLaunchKernelGGL(k_hist_conv, dim3(hb + cb), dim3(256), 0, stream, dst, E, deg, rank, hb,
                     emb, embh, n4);
  // scan chain
  hipLaunchKernelGGL(k_scanA, dim3(nb), dim3(256), 0, stream, deg, offs, bsum, N);
  hipLaunchKernelGGL(k_scanB, dim3(1), dim3(128), 0, stream, bsum, offs, nb, E, N);
  hipLaunchKernelGGL(k_scanC, dim3(nb), dim3(256), 0, stream, offs, bsum, N);
  // K_E: gemm  U  scatter (independent work, overlapped)
  if (big) {
    hipLaunchKernelGGL(k_gemm_scatter<true>, dim3(gb + sb), dim3(256), 0, stream,
                       emb, embh, Wt, xl, xr, src, dst, offs, rank, csr, att, blr, N, E, gb);
  } else {
    hipLaunchKernelGGL(k_gemm_scatter<false>, dim3(gb + sb), dim3(256), 0, stream,
                       emb, embh, Wt, xl, xr, src, dst, offs, rank, csr, att, blr, N, E, gb);
  }
  // edge pass
  hipLaunchKernelGGL(k_edge, dim3((N + 3) / 4), dim3(256), 0, stream, xl, xr, blr, offs, csr,
                     att, bias, out, N);
}

// Round 3
// 469.503 us; speedup vs baseline: 1.1089x; 1.1089x over previous
//
#include <hip/hip_runtime.h>
#include <hip/hip_bf16.h>
#include <stdint.h>

#define D_IN 256
#define NEG 0.2f
#define LOG2E 1.44269504f

typedef unsigned short bf16_t;
typedef __attribute__((ext_vector_type(8))) short bfrag;   // 8 bf16 = 4 VGPR
typedef __attribute__((ext_vector_type(4))) float ffrag;   // MFMA C/D

__device__ __forceinline__ bf16_t f2bf(float f) {
  unsigned int u = __float_as_uint(f);
  unsigned int r = u + 0x7FFFu + ((u >> 16) & 1u);   // RNE
  return (bf16_t)(r >> 16);
}
__device__ __forceinline__ unsigned int pk2(float a, float b) {
  return (unsigned int)f2bf(a) | ((unsigned int)f2bf(b) << 16);
}
__device__ __forceinline__ void ld4bf(const bf16_t* p, float* f) {
  uint2 u = *(const uint2*)p;
  f[0] = __uint_as_float(u.x << 16);
  f[1] = __uint_as_float(u.x & 0xFFFF0000u);
  f[2] = __uint_as_float(u.y << 16);
  f[3] = __uint_as_float(u.y & 0xFFFF0000u);
}

// ---------------- K0: zero deg  UNION  Wt transpose+convert ----------------
__global__ __launch_bounds__(256) void k_zero_wt(int* __restrict__ deg, int n, int zb,
                                                 const float* __restrict__ Wl,
                                                 const float* __restrict__ Wr,
                                                 bf16_t* __restrict__ Wt) {
  const int b = blockIdx.x, tid = threadIdx.x;
  if (b < zb) {
    int i = b * 256 + tid;
    if (i < n) deg[i] = 0;
  } else {
    int gid = (b - zb) * 256 + tid;   // 2*256*256 total
    int w = gid >> 16;
    int c = (gid >> 8) & 255;
    int k = gid & 255;
    const float* W = w ? Wr : Wl;
    Wt[gid] = f2bf(W[k * 256 + c]);
  }
}

// ---------------- K_A: hist(+rank)  UNION  emb fp32->bf16 conv ----------------
__global__ __launch_bounds__(256) void k_hist_conv(const int* __restrict__ dst, int E,
                                                   int* __restrict__ deg, int* __restrict__ rank,
                                                   int hb,
                                                   const float* __restrict__ emb,
                                                   bf16_t* __restrict__ embh, int n4) {
  const int b = blockIdx.x, tid = threadIdx.x;
  if (b < hb) {
    int e = b * 256 + tid;
    if (e < E) rank[e] = atomicAdd(&deg[dst[e]], 1);
  } else {
    int i = (b - hb) * 256 + tid;
    if (i < n4) {
      float4 f = ((const float4*)emb)[i];
      uint2 o;
      o.x = pk2(f.x, f.y);
      o.y = pk2(f.z, f.w);
      ((uint2*)embh)[i] = o;
    }
  }
}

// ---------------- scan chain ----------------
__global__ __launch_bounds__(256) void k_scanA(const int* __restrict__ deg,
                                               int* __restrict__ offs,
                                               int* __restrict__ bsum, int N) {
  __shared__ int sh[256];
  int t = threadIdx.x;
  int base = blockIdx.x * 1024 + t * 4;
  int v[4];
#pragma unroll
  for (int q = 0; q < 4; q++) v[q] = (base + q < N) ? deg[base + q] : 0;
  int ls = v[0] + v[1] + v[2] + v[3];
  sh[t] = ls;
  __syncthreads();
  for (int ofs = 1; ofs < 256; ofs <<= 1) {
    int x = (t >= ofs) ? sh[t - ofs] : 0;
    __syncthreads();
    sh[t] += x;
    __syncthreads();
  }
  int run = sh[t] - ls;
#pragma unroll
  for (int q = 0; q < 4; q++) {
    if (base + q < N) offs[base + q] = run;
    run += v[q];
  }
  if (t == 255) bsum[blockIdx.x] = sh[255];
}

__global__ __launch_bounds__(128) void k_scanB(int* __restrict__ bsum, int* __restrict__ offs,
                                               int nb, int E, int N) {
  __shared__ int sh[128];
  int t = threadIdx.x;
  int v = (t < nb) ? bsum[t] : 0;
  sh[t] = v;
  __syncthreads();
  for (int ofs = 1; ofs < 128; ofs <<= 1) {
    int x = (t >= ofs) ? sh[t - ofs] : 0;
    __syncthreads();
    sh[t] += x;
    __syncthreads();
  }
  if (t < nb) bsum[t] = sh[t] - v;
  if (t == 0) offs[N] = E;
}

__global__ __launch_bounds__(256) void k_scanC(int* __restrict__ offs,
                                               const int* __restrict__ bsum, int N) {
  int t = threadIdx.x;
  int base = blockIdx.x * 1024 + t * 4;
  int add = bsum[blockIdx.x];
#pragma unroll
  for (int q = 0; q < 4; q++) {
    int i = base + q;
    if (i < N) offs[i] += add;
  }
}

// ---------------- K_E: MFMA GEMM  UNION  scatter (no atomic) ----------------
// gemm: 128x128 tile, BK=32, 4 waves x (64x64 via 4x4 MFMA 16x16x32)
// stores |a_c|-scaled bf16 (k_edge unscales at the end).
// XCD swizzle: co-locate the 4 sibling blocks (same A row-tile) on one XCD.
template <bool USEBF>
__global__ __launch_bounds__(256) void k_gemm_scatter(
    const float* __restrict__ emb, const bf16_t* __restrict__ embh,
    const bf16_t* __restrict__ Wt, bf16_t* __restrict__ xl, bf16_t* __restrict__ xr,
    const int* __restrict__ src, const int* __restrict__ dst,
    const int* __restrict__ offs, const int* __restrict__ rank, int* __restrict__ csr,
    const float* __restrict__ att,
    int N, int E, int gb) {
  __shared__ bf16_t As[128][40];
  __shared__ bf16_t Bs[128][40];
  const int tid = threadIdx.x;

  if ((int)blockIdx.x >= gb) {   // -------- scatter branch --------
    int e = ((int)blockIdx.x - gb) * 256 + tid;
    if (e < E) {
      int pos = offs[dst[e]] + rank[e];
      csr[pos] = src[e];
    }
    return;
  }

  // -------- gemm branch: bijective chunked XCD swizzle (8 XCDs) --------
  int g = (int)blockIdx.x;
  {
    int xcd = g & 7, slot = g >> 3;
    int q8 = gb >> 3, r8 = gb & 7;
    g = (xcd < r8 ? xcd * (q8 + 1) : r8 * (q8 + 1) + (xcd - r8) * q8) + slot;
  }
  const int bx = g >> 2, nt = g & 3;  // nt: 0,1->Wl; 2,3->Wr
  const int row0 = bx * 128;
  const bf16_t* Wp = Wt + (size_t)(nt >> 1) * 65536;
  bf16_t* dstp = (nt < 2) ? xl : xr;
  const int c0 = (nt & 1) * 128;

  const int wave = tid >> 6, lane = tid & 63;
  const int m0w = (wave & 1) * 64, n0w = (wave >> 1) * 64;
  const int fr = lane & 15;
  const int aq = (lane >> 4) * 8;

  const int srow = tid >> 1, sseg = (tid & 1) * 16;
  const int grow = row0 + srow;
  const bool aok = grow < N;
  const bf16_t* bp = Wp + (size_t)(c0 + srow) * 256 + sseg;

  ffrag acc[4][4];
#pragma unroll
  for (int mi = 0; mi < 4; mi++)
#pragma unroll
    for (int ni = 0; ni < 4; ni++) acc[mi][ni] = (ffrag)0.f;

  for (int k0 = 0; k0 < 256; k0 += 32) {
    uint4 pa0 = make_uint4(0, 0, 0, 0), pa1 = pa0;
    if (USEBF) {
      const bf16_t* ap = embh + (size_t)grow * 256 + sseg;
      if (aok) {
        pa0 = *(const uint4*)(ap + k0);
        pa1 = *(const uint4*)(ap + k0 + 8);
      }
    } else {
      const float* ap = emb + (size_t)grow * 256 + sseg;
      float4 f0 = make_float4(0, 0, 0, 0), f1 = f0, f2 = f0, f3 = f0;
      if (aok) {
        f0 = *(const float4*)(ap + k0);
        f1 = *(const float4*)(ap + k0 + 4);
        f2 = *(const float4*)(ap + k0 + 8);
        f3 = *(const float4*)(ap + k0 + 12);
      }
      pa0.x = pk2(f0.x, f0.y); pa0.y = pk2(f0.z, f0.w);
      pa0.z = pk2(f1.x, f1.y); pa0.w = pk2(f1.z, f1.w);
      pa1.x = pk2(f2.x, f2.y); pa1.y = pk2(f2.z, f2.w);
      pa1.z = pk2(f3.x, f3.y); pa1.w = pk2(f3.z, f3.w);
    }
    uint4 b0 = *(const uint4*)(bp + k0);
    uint4 b1 = *(const uint4*)(bp + k0 + 8);
    __syncthreads();
    *(uint4*)&As[srow][sseg] = pa0;
    *(uint4*)&As[srow][sseg + 8] = pa1;
    *(uint4*)&Bs[srow][sseg] = b0;
    *(uint4*)&Bs[srow][sseg + 8] = b1;
    __syncthreads();

    bfrag af[4], bfv[4];
#pragma unroll
    for (int mi = 0; mi < 4; mi++) af[mi] = *(const bfrag*)&As[m0w + mi * 16 + fr][aq];
#pragma unroll
    for (int ni = 0; ni < 4; ni++) bfv[ni] = *(const bfrag*)&Bs[n0w + ni * 16 + fr][aq];
#pragma unroll
    for (int mi = 0; mi < 4; mi++)
#pragma unroll
      for (int ni = 0; ni < 4; ni++)
        acc[mi][ni] = __builtin_amdgcn_mfma_f32_16x16x32_bf16(af[mi], bfv[ni], acc[mi][ni], 0, 0, 0);
  }

  const int rbase = m0w + (lane >> 4) * 4;

  // scaled bf16 store: ail/air = |a_c| * x_c  (k_edge unscales)
  float absa[4];
#pragma unroll
  for (int ni = 0; ni < 4; ni++) absa[ni] = fabsf(att[c0 + n0w + ni * 16 + fr]);
#pragma unroll
  for (int mi = 0; mi < 4; mi++) {
#pragma unroll
    for (int ni = 0; ni < 4; ni++) {
      int col = c0 + n0w + ni * 16 + fr;
#pragma unroll
      for (int rr = 0; rr < 4; rr++) {
        int row = row0 + rbase + mi * 16 + rr;
        if (row < N) dstp[(size_t)row * 256 + col] = f2bf(acc[mi][ni][rr] * absa[ni]);
      }
    }
  }
}

// ---------------- fused edge pass (R2 layout + leaky decomposition) ----------------
// one wave per dst node; lane = (head = lane>>4) x (4-ch group = lane&15), 4 ch/lane.
// stored ail=|a|*xl, air=|a|*xr (bf16). Per-channel identity:
//   a*leaky(xl+xr) = 0.6*sgn*(ail + (2/3)|ail+air|) + 0.6*sgn*air
// second term is per-node (pre). Inner loop: add, fma(K,|t|,x), fma(sgn,u,p) = 3 VALU/ch.
// scores ~ N(0,0.04) -> plain exp2 overflow-safe (validated earlier runs).
__device__ __forceinline__ float wred16(float p) {
  p += __shfl_xor(p, 1);
  p += __shfl_xor(p, 2);
  p += __shfl_xor(p, 4);
  p += __shfl_xor(p, 8);
  return p;
}

__global__ __launch_bounds__(256) void k_edge(const bf16_t* __restrict__ ail,
                                              const bf16_t* __restrict__ air,
                                              const int* __restrict__ offs,
                                              const int* __restrict__ csr,
                                              const float* __restrict__ att,
                                              const float* __restrict__ bias,
                                              float* __restrict__ out, int N) {
  const int wv = threadIdx.x >> 6;
  const int lane = threadIdx.x & 63;
  const int i = blockIdx.x * 4 + wv;
  if (i >= N) return;
  const int cbase = (lane >> 4) * 64 + (lane & 15) * 4;
  const float K = 0.66666669f;        // 2/3
  const float C = 0.6f * LOG2E;       // folds the 0.6 scale + log2e into exp2 arg

  const float4 avv = *(const float4*)(att + cbase);
  const float sg[4] = {copysignf(1.f, avv.x), copysignf(1.f, avv.y),
                       copysignf(1.f, avv.z), copysignf(1.f, avv.w)};

  float xrv[4];
  ld4bf(air + (size_t)i * 256 + cbase, xrv);

  // per-node term: pre = C * sum_c sgn*air  (= 0.6*log2e * (a . xr_i))
  float pb = 0.f;
#pragma unroll
  for (int q = 0; q < 4; q++) pb = fmaf(sg[q], xrv[q], pb);
  const float pre = C * wred16(pb);

  const bf16_t* ailc = ail + cbase;

  // self loop
  float d, acc[4];
  {
    float x[4];
    ld4bf(ailc + ((size_t)(unsigned)i << 8), x);
    float p = 0.f;
#pragma unroll
    for (int q = 0; q < 4; q++) {
      float t = x[q] + xrv[q];
      float u = fmaf(K, fabsf(t), x[q]);
      p = fmaf(sg[q], u, p);
    }
    p = wred16(p);
    float e = exp2f(fmaf(C, p, pre));
    d = e;
#pragma unroll
    for (int q = 0; q < 4; q++) acc[q] = e * x[q];
  }

  int k = offs[i];
  const int kend = offs[i + 1];

  for (; k + 4 <= kend; k += 4) {
    int j0 = csr[k], j1 = csr[k + 1], j2 = csr[k + 2], j3 = csr[k + 3];
    float x0[4], x1[4], x2[4], x3[4];
    ld4bf(ailc + ((size_t)(unsigned)j0 << 8), x0);
    ld4bf(ailc + ((size_t)(unsigned)j1 << 8), x1);
    ld4bf(ailc + ((size_t)(unsigned)j2 << 8), x2);
    ld4bf(ailc + ((size_t)(unsigned)j3 << 8), x3);
    float p0 = 0.f, p1 = 0.f, p2 = 0.f, p3 = 0.f;
#pragma unroll
    for (int q = 0; q < 4; q++) {
      float t0 = x0[q] + xrv[q], t1 = x1[q] + xrv[q];
      float t2 = x2[q] + xrv[q], t3 = x3[q] + xrv[q];
      float u0 = fmaf(K, fabsf(t0), x0[q]);
      float u1 = fmaf(K, fabsf(t1), x1[q]);
      float u2 = fmaf(K, fabsf(t2), x2[q]);
      float u3 = fmaf(K, fabsf(t3), x3[q]);
      p0 = fmaf(sg[q], u0, p0); p1 = fmaf(sg[q], u1, p1);
      p2 = fmaf(sg[q], u2, p2); p3 = fmaf(sg[q], u3, p3);
    }
    float e0 = exp2f(fmaf(C, wred16(p0), pre));
    float e1 = exp2f(fmaf(C, wred16(p1), pre));
    float e2 = exp2f(fmaf(C, wred16(p2), pre));
    float e3 = exp2f(fmaf(C, wred16(p3), pre));
    d += (e0 + e1) + (e2 + e3);
#pragma unroll
    for (int q = 0; q < 4; q++) {
      acc[q] = fmaf(e0, x0[q], acc[q]);
      acc[q] = fmaf(e1, x1[q], acc[q]);
      acc[q] = fmaf(e2, x2[q], acc[q]);
      acc[q] = fmaf(e3, x3[q], acc[q]);
    }
  }
  for (; k < kend; ++k) {
    int j = csr[k];
    float x[4];
    ld4bf(ailc + ((size_t)(unsigned)j << 8), x);
    float p = 0.f;
#pragma unroll
    for (int q = 0; q < 4; q++) {
      float t = x[q] + xrv[q];
      float u = fmaf(K, fabsf(t), x[q]);
      p = fmaf(sg[q], u, p);
    }
    p = wred16(p);
    float e = exp2f(fmaf(C, p, pre));
    d += e;
#pragma unroll
    for (int q = 0; q < 4; q++) acc[q] = fmaf(e, x[q], acc[q]);
  }

  // per-head normalize, unscale by 1/|a_c|, head-mean (xor 16, 32)
  const float invd = 0.25f / d;
  const float inva[4] = {1.f / fabsf(avv.x), 1.f / fabsf(avv.y),
                         1.f / fabsf(avv.z), 1.f / fabsf(avv.w)};
  float v[4];
#pragma unroll
  for (int q = 0; q < 4; q++) v[q] = acc[q] * invd * inva[q];
#pragma unroll
  for (int q = 0; q < 4; q++) {
    v[q] += __shfl_xor(v[q], 16);
    v[q] += __shfl_xor(v[q], 32);
  }
  if ((lane >> 4) == 0) {
    const float4 bq = *(const float4*)(bias + (lane & 15) * 4);
    const float bb[4] = {bq.x, bq.y, bq.z, bq.w};
    float o[4];
#pragma unroll
    for (int q = 0; q < 4; q++) {
      float x = v[q] + bb[q];
      o[q] = x > 0.f ? x : (__expf(x) - 1.f);  // elu
    }
    *(float4*)(out + (size_t)i * 64 + (lane & 15) * 4) = make_float4(o[0], o[1], o[2], o[3]);
  }
}

extern "C" void kernel_launch(void* const* d_in, const int* in_sizes, int n_in,
                              void* d_out, int out_size, void* d_ws, size_t ws_size,
                              hipStream_t stream) {
  const int* edge = (const int*)d_in[1];   // [2][E] : row0 = src, row1 = dst
  const float* emb = (const float*)d_in[2];
  const float* Wl = (const float*)d_in[3];
  const float* Wr = (const float*)d_in[4];
  const float* att = (const float*)d_in[5];
  const float* bias = (const float*)d_in[6];
  float* out = (float*)d_out;

  const int E = in_sizes[1] / 2;
  const int N = in_sizes[2] / D_IN;
  const int* src = edge;
  const int* dst = edge + E;

  // strictly disjoint carve; embh (gated) at the end
  const size_t NB = (size_t)N * 256 * 2;
  char* w = (char*)d_ws;
  bf16_t* xl = (bf16_t*)w;  w += NB;            // ail = |a|*xl (bf16)
  bf16_t* xr = (bf16_t*)w;  w += NB;            // air = |a|*xr (bf16)
  bf16_t* Wt = (bf16_t*)w;  w += (size_t)2 * 256 * 256 * 2;
  int* offs = (int*)w;      w += ((size_t)N + 64) * 4;
  int* deg = (int*)w;       w += ((size_t)N + 64) * 4;
  int* bsum = (int*)w;      w += 1024;
  int* rank = (int*)w;      w += (size_t)E * 4;
  int* csr = (int*)w;       w += (size_t)E * 4;
  bf16_t* embh = (bf16_t*)w;
  const size_t need_big = (size_t)(w - (char*)d_ws) + NB;
  const bool big = ws_size >= need_big;   // ws_size constant -> same path every call

  const int nb = (N + 1023) / 1024;
  const int zb = (N + 255) / 256;
  const int hb = (E + 255) / 256;
  const int n4 = big ? N * 64 : 0;            // conv work items /4
  const int cb = big ? (n4 + 255) / 256 : 0;  // conv blocks
  const int gb = ((N + 127) / 128) * 4;       // gemm blocks
  const int sb = hb;                          // scatter blocks

  // K0: zero deg  U  Wt convert
  hipLaunchKernelGGL(k_zero_wt, dim3(zb + 512), dim3(256), 0, stream, deg, N, zb, Wl, Wr, Wt);
  // K_A: hist(+rank)  U  emb->bf16 conv
  hipLaunchKernelGGL(k_hist_conv, dim3(hb + cb), dim3(256), 0, stream, dst, E, deg, rank, hb,
                     emb, embh, n4);
  // scan chain
  hipLaunchKernelGGL(k_scanA, dim3(nb), dim3(256), 0, stream, deg, offs, bsum, N);
  hipLaunchKernelGGL(k_scanB, dim3(1), dim3(128), 0, stream, bsum, offs, nb, E, N);
  hipLaunchKernelGGL(k_scanC, dim3(nb), dim3(256), 0, stream, offs, bsum, N);
  // K_E: gemm  U  scatter (independent work, overlapped)
  if (big) {
    hipLaunchKernelGGL(k_gemm_scatter<true>, dim3(gb + sb), dim3(256), 0, stream,
                       emb, embh, Wt, xl, xr, src, dst, offs, rank, csr, att, N, E, gb);
  } else {
    hipLaunchKernelGGL(k_gemm_scatter<false>, dim3(gb + sb), dim3(256), 0, stream,
                       emb, embh, Wt, xl, xr, src, dst, offs, rank, csr, att, N, E, gb);
  }
  // edge pass
  hipLaunchKernelGGL(k_edge, dim3((N + 3) / 4), dim3(256), 0, stream, xl, xr, offs, csr,
                     att, bias, out, N);
}

// Round 5
// 463.992 us; speedup vs baseline: 1.1221x; 1.0119x over previous
//
#include <hip/hip_runtime.h>
#include <hip/hip_bf16.h>
#include <stdint.h>

#define D_IN 256
#define NEG 0.2f
#define LOG2E 1.44269504f

typedef unsigned short bf16_t;
typedef __attribute__((ext_vector_type(8))) short bfrag;   // 8 bf16 = 4 VGPR
typedef __attribute__((ext_vector_type(4))) float ffrag;   // MFMA C/D

__device__ __forceinline__ bf16_t f2bf(float f) {
  unsigned int u = __float_as_uint(f);
  unsigned int r = u + 0x7FFFu + ((u >> 16) & 1u);   // RNE
  return (bf16_t)(r >> 16);
}
__device__ __forceinline__ unsigned int pk2(float a, float b) {
  return (unsigned int)f2bf(a) | ((unsigned int)f2bf(b) << 16);
}
__device__ __forceinline__ void ld4bf(const bf16_t* p, float* f) {
  uint2 u = *(const uint2*)p;
  f[0] = __uint_as_float(u.x << 16);
  f[1] = __uint_as_float(u.x & 0xFFFF0000u);
  f[2] = __uint_as_float(u.y << 16);
  f[3] = __uint_as_float(u.y & 0xFFFF0000u);
}
// uniform base + 32-bit byte offset -> saddr global_load form (1 VALU addr)
__device__ __forceinline__ void ld4bf_off(const bf16_t* base, unsigned boff, float* f) {
  uint2 u = *(const uint2*)((const char*)base + boff);
  f[0] = __uint_as_float(u.x << 16);
  f[1] = __uint_as_float(u.x & 0xFFFF0000u);
  f[2] = __uint_as_float(u.y << 16);
  f[3] = __uint_as_float(u.y & 0xFFFF0000u);
}

// ---------------- K0: zero deg  UNION  Wt transpose+convert ----------------
__global__ __launch_bounds__(256) void k_zero_wt(int* __restrict__ deg, int n, int zb,
                                                 const float* __restrict__ Wl,
                                                 const float* __restrict__ Wr,
                                                 bf16_t* __restrict__ Wt) {
  const int b = blockIdx.x, tid = threadIdx.x;
  if (b < zb) {
    int i = b * 256 + tid;
    if (i < n) deg[i] = 0;
  } else {
    int gid = (b - zb) * 256 + tid;   // 2*256*256 total
    int w = gid >> 16;
    int c = (gid >> 8) & 255;
    int k = gid & 255;
    const float* W = w ? Wr : Wl;
    Wt[gid] = f2bf(W[k * 256 + c]);
  }
}

// ---------------- K_A: hist(+rank)  UNION  emb fp32->bf16 conv ----------------
__global__ __launch_bounds__(256) void k_hist_conv(const int* __restrict__ dst, int E,
                                                   int* __restrict__ deg, int* __restrict__ rank,
                                                   int hb,
                                                   const float* __restrict__ emb,
                                                   bf16_t* __restrict__ embh, int n4) {
  const int b = blockIdx.x, tid = threadIdx.x;
  if (b < hb) {
    int e = b * 256 + tid;
    if (e < E) rank[e] = atomicAdd(&deg[dst[e]], 1);
  } else {
    int i = (b - hb) * 256 + tid;
    if (i < n4) {
      float4 f = ((const float4*)emb)[i];
      uint2 o;
      o.x = pk2(f.x, f.y);
      o.y = pk2(f.z, f.w);
      ((uint2*)embh)[i] = o;
    }
  }
}

// ---------------- scan chain ----------------
__global__ __launch_bounds__(256) void k_scanA(const int* __restrict__ deg,
                                               int* __restrict__ offs,
                                               int* __restrict__ bsum, int N) {
  __shared__ int sh[256];
  int t = threadIdx.x;
  int base = blockIdx.x * 1024 + t * 4;
  int v[4];
#pragma unroll
  for (int q = 0; q < 4; q++) v[q] = (base + q < N) ? deg[base + q] : 0;
  int ls = v[0] + v[1] + v[2] + v[3];
  sh[t] = ls;
  __syncthreads();
  for (int ofs = 1; ofs < 256; ofs <<= 1) {
    int x = (t >= ofs) ? sh[t - ofs] : 0;
    __syncthreads();
    sh[t] += x;
    __syncthreads();
  }
  int run = sh[t] - ls;
#pragma unroll
  for (int q = 0; q < 4; q++) {
    if (base + q < N) offs[base + q] = run;
    run += v[q];
  }
  if (t == 255) bsum[blockIdx.x] = sh[255];
}

__global__ __launch_bounds__(128) void k_scanB(int* __restrict__ bsum, int* __restrict__ offs,
                                               int nb, int E, int N) {
  __shared__ int sh[128];
  int t = threadIdx.x;
  int v = (t < nb) ? bsum[t] : 0;
  sh[t] = v;
  __syncthreads();
  for (int ofs = 1; ofs < 128; ofs <<= 1) {
    int x = (t >= ofs) ? sh[t - ofs] : 0;
    __syncthreads();
    sh[t] += x;
    __syncthreads();
  }
  if (t < nb) bsum[t] = sh[t] - v;
  if (t == 0) offs[N] = E;
}

__global__ __launch_bounds__(256) void k_scanC(int* __restrict__ offs,
                                               const int* __restrict__ bsum, int N) {
  int t = threadIdx.x;
  int base = blockIdx.x * 1024 + t * 4;
  int add = bsum[blockIdx.x];
#pragma unroll
  for (int q = 0; q < 4; q++) {
    int i = base + q;
    if (i < N) offs[i] += add;
  }
}

// ---------------- K_E: MFMA GEMM  UNION  scatter (no atomic) ----------------
// gemm: 128x128 tile, BK=32, 4 waves x (64x64 via 4x4 MFMA 16x16x32)
// stores |a_c|-scaled bf16 (k_edge unscales at the end).
// XCD swizzle: co-locate the 4 sibling blocks (same A row-tile) on one XCD.
template <bool USEBF>
__global__ __launch_bounds__(256) void k_gemm_scatter(
    const float* __restrict__ emb, const bf16_t* __restrict__ embh,
    const bf16_t* __restrict__ Wt, bf16_t* __restrict__ xl, bf16_t* __restrict__ xr,
    const int* __restrict__ src, const int* __restrict__ dst,
    const int* __restrict__ offs, const int* __restrict__ rank, int* __restrict__ csr,
    const float* __restrict__ att,
    int N, int E, int gb) {
  __shared__ bf16_t As[128][40];
  __shared__ bf16_t Bs[128][40];
  const int tid = threadIdx.x;

  if ((int)blockIdx.x >= gb) {   // -------- scatter branch --------
    int e = ((int)blockIdx.x - gb) * 256 + tid;
    if (e < E) {
      int pos = offs[dst[e]] + rank[e];
      csr[pos] = src[e];
    }
    return;
  }

  // -------- gemm branch: bijective chunked XCD swizzle (8 XCDs) --------
  int g = (int)blockIdx.x;
  {
    int xcd = g & 7, slot = g >> 3;
    int q8 = gb >> 3, r8 = gb & 7;
    g = (xcd < r8 ? xcd * (q8 + 1) : r8 * (q8 + 1) + (xcd - r8) * q8) + slot;
  }
  const int bx = g >> 2, nt = g & 3;  // nt: 0,1->Wl; 2,3->Wr
  const int row0 = bx * 128;
  const bf16_t* Wp = Wt + (size_t)(nt >> 1) * 65536;
  bf16_t* dstp = (nt < 2) ? xl : xr;
  const int c0 = (nt & 1) * 128;

  const int wave = tid >> 6, lane = tid & 63;
  const int m0w = (wave & 1) * 64, n0w = (wave >> 1) * 64;
  const int fr = lane & 15;
  const int aq = (lane >> 4) * 8;

  const int srow = tid >> 1, sseg = (tid & 1) * 16;
  const int grow = row0 + srow;
  const bool aok = grow < N;
  const bf16_t* bp = Wp + (size_t)(c0 + srow) * 256 + sseg;

  ffrag acc[4][4];
#pragma unroll
  for (int mi = 0; mi < 4; mi++)
#pragma unroll
    for (int ni = 0; ni < 4; ni++) acc[mi][ni] = (ffrag)0.f;

  for (int k0 = 0; k0 < 256; k0 += 32) {
    uint4 pa0 = make_uint4(0, 0, 0, 0), pa1 = pa0;
    if (USEBF) {
      const bf16_t* ap = embh + (size_t)grow * 256 + sseg;
      if (aok) {
        pa0 = *(const uint4*)(ap + k0);
        pa1 = *(const uint4*)(ap + k0 + 8);
      }
    } else {
      const float* ap = emb + (size_t)grow * 256 + sseg;
      float4 f0 = make_float4(0, 0, 0, 0), f1 = f0, f2 = f0, f3 = f0;
      if (aok) {
        f0 = *(const float4*)(ap + k0);
        f1 = *(const float4*)(ap + k0 + 4);
        f2 = *(const float4*)(ap + k0 + 8);
        f3 = *(const float4*)(ap + k0 + 12);
      }
      pa0.x = pk2(f0.x, f0.y); pa0.y = pk2(f0.z, f0.w);
      pa0.z = pk2(f1.x, f1.y); pa0.w = pk2(f1.z, f1.w);
      pa1.x = pk2(f2.x, f2.y); pa1.y = pk2(f2.z, f2.w);
      pa1.z = pk2(f3.x, f3.y); pa1.w = pk2(f3.z, f3.w);
    }
    uint4 b0 = *(const uint4*)(bp + k0);
    uint4 b1 = *(const uint4*)(bp + k0 + 8);
    __syncthreads();
    *(uint4*)&As[srow][sseg] = pa0;
    *(uint4*)&As[srow][sseg + 8] = pa1;
    *(uint4*)&Bs[srow][sseg] = b0;
    *(uint4*)&Bs[srow][sseg + 8] = b1;
    __syncthreads();

    bfrag af[4], bfv[4];
#pragma unroll
    for (int mi = 0; mi < 4; mi++) af[mi] = *(const bfrag*)&As[m0w + mi * 16 + fr][aq];
#pragma unroll
    for (int ni = 0; ni < 4; ni++) bfv[ni] = *(const bfrag*)&Bs[n0w + ni * 16 + fr][aq];
#pragma unroll
    for (int mi = 0; mi < 4; mi++)
#pragma unroll
      for (int ni = 0; ni < 4; ni++)
        acc[mi][ni] = __builtin_amdgcn_mfma_f32_16x16x32_bf16(af[mi], bfv[ni], acc[mi][ni], 0, 0, 0);
  }

  const int rbase = m0w + (lane >> 4) * 4;

  // scaled bf16 store: ail/air = |a_c| * x_c  (k_edge unscales)
  float absa[4];
#pragma unroll
  for (int ni = 0; ni < 4; ni++) absa[ni] = fabsf(att[c0 + n0w + ni * 16 + fr]);
#pragma unroll
  for (int mi = 0; mi < 4; mi++) {
#pragma unroll
    for (int ni = 0; ni < 4; ni++) {
      int col = c0 + n0w + ni * 16 + fr;
#pragma unroll
      for (int rr = 0; rr < 4; rr++) {
        int row = row0 + rbase + mi * 16 + rr;
        if (row < N) dstp[(size_t)row * 256 + col] = f2bf(acc[mi][ni][rr] * absa[ni]);
      }
    }
  }
}

// ---------------- fused edge pass ----------------
// one wave per dst node; lane = (head = lane>>4) x (4-ch group = lane&15), 4 ch/lane.
// stored ail=|a|*xl, air=|a|*xr (bf16). Per-channel identity:
//   a*leaky(xl+xr) = 0.6*sgn*(ail + (2/3)|ail+air|) + 0.6*sgn*air
// second term is per-node (pre). Inner loop: add, fma(K,|t|,x), fma(sgn,u,p) = 3 VALU/ch.
// Codegen discipline: direct v_exp via __builtin_amdgcn_exp2f (not OCML exp2f);
// uniform-base + 32-bit byte-offset loads -> saddr form; v_rcp for per-node
// reciprocals. scores ~ N(0,0.04) -> plain exp2 overflow-safe.
__device__ __forceinline__ float wred16(float p) {
  p += __shfl_xor(p, 1);
  p += __shfl_xor(p, 2);
  p += __shfl_xor(p, 4);
  p += __shfl_xor(p, 8);
  return p;
}

__global__ __launch_bounds__(256) void k_edge(const bf16_t* __restrict__ ail,
                                              const bf16_t* __restrict__ air,
                                              const int* __restrict__ offs,
                                              const int* __restrict__ csr,
                                              const float* __restrict__ att,
                                              const float* __restrict__ bias,
                                              float* __restrict__ out, int N) {
  const int wv = threadIdx.x >> 6;
  const int lane = threadIdx.x & 63;
  const int i = blockIdx.x * 4 + wv;
  if (i >= N) return;
  const int cbase = (lane >> 4) * 64 + (lane & 15) * 4;
  const unsigned cb2 = (unsigned)cbase * 2;   // byte offset within a 512B row
  const float K = 0.66666669f;        // 2/3
  const float C = 0.6f * LOG2E;       // folds the 0.6 scale + log2e into exp2 arg

  const float4 avv = *(const float4*)(att + cbase);
  const float sg[4] = {copysignf(1.f, avv.x), copysignf(1.f, avv.y),
                       copysignf(1.f, avv.z), copysignf(1.f, avv.w)};

  float xrv[4];
  ld4bf_off(air, ((unsigned)i << 9) + cb2, xrv);

  // per-node term: pre = C * sum_c sgn*air  (= 0.6*log2e * (a . xr_i))
  float pb = 0.f;
#pragma unroll
  for (int q = 0; q < 4; q++) pb = fmaf(sg[q], xrv[q], pb);
  const float pre = C * wred16(pb);

  // self loop
  float d, acc[4];
  {
    float x[4];
    ld4bf_off(ail, ((unsigned)i << 9) + cb2, x);
    float p = 0.f;
#pragma unroll
    for (int q = 0; q < 4; q++) {
      float t = x[q] + xrv[q];
      float u = fmaf(K, fabsf(t), x[q]);
      p = fmaf(sg[q], u, p);
    }
    p = wred16(p);
    float e = __builtin_amdgcn_exp2f(fmaf(C, p, pre));
    d = e;
#pragma unroll
    for (int q = 0; q < 4; q++) acc[q] = e * x[q];
  }

  int k = offs[i];
  const int kend = offs[i + 1];

  for (; k + 4 <= kend; k += 4) {
    int j0 = csr[k], j1 = csr[k + 1], j2 = csr[k + 2], j3 = csr[k + 3];
    float x0[4], x1[4], x2[4], x3[4];
    ld4bf_off(ail, ((unsigned)j0 << 9) + cb2, x0);
    ld4bf_off(ail, ((unsigned)j1 << 9) + cb2, x1);
    ld4bf_off(ail, ((unsigned)j2 << 9) + cb2, x2);
    ld4bf_off(ail, ((unsigned)j3 << 9) + cb2, x3);
    float p0 = 0.f, p1 = 0.f, p2 = 0.f, p3 = 0.f;
#pragma unroll
    for (int q = 0; q < 4; q++) {
      float t0 = x0[q] + xrv[q], t1 = x1[q] + xrv[q];
      float t2 = x2[q] + xrv[q], t3 = x3[q] + xrv[q];
      float u0 = fmaf(K, fabsf(t0), x0[q]);
      float u1 = fmaf(K, fabsf(t1), x1[q]);
      float u2 = fmaf(K, fabsf(t2), x2[q]);
      float u3 = fmaf(K, fabsf(t3), x3[q]);
      p0 = fmaf(sg[q], u0, p0); p1 = fmaf(sg[q], u1, p1);
      p2 = fmaf(sg[q], u2, p2); p3 = fmaf(sg[q], u3, p3);
    }
    float e0 = __builtin_amdgcn_exp2f(fmaf(C, wred16(p0), pre));
    float e1 = __builtin_amdgcn_exp2f(fmaf(C, wred16(p1), pre));
    float e2 = __builtin_amdgcn_exp2f(fmaf(C, wred16(p2), pre));
    float e3 = __builtin_amdgcn_exp2f(fmaf(C, wred16(p3), pre));
    d += (e0 + e1) + (e2 + e3);
#pragma unroll
    for (int q = 0; q < 4; q++) {
      acc[q] = fmaf(e0, x0[q], acc[q]);
      acc[q] = fmaf(e1, x1[q], acc[q]);
      acc[q] = fmaf(e2, x2[q], acc[q]);
      acc[q] = fmaf(e3, x3[q], acc[q]);
    }
  }
  for (; k < kend; ++k) {
    int j = csr[k];
    float x[4];
    ld4bf_off(ail, ((unsigned)j << 9) + cb2, x);
    float p = 0.f;
#pragma unroll
    for (int q = 0; q < 4; q++) {
      float t = x[q] + xrv[q];
      float u = fmaf(K, fabsf(t), x[q]);
      p = fmaf(sg[q], u, p);
    }
    p = wred16(p);
    float e = __builtin_amdgcn_exp2f(fmaf(C, p, pre));
    d += e;
#pragma unroll
    for (int q = 0; q < 4; q++) acc[q] = fmaf(e, x[q], acc[q]);
  }

  // per-head normalize, unscale by 1/|a_c| (v_rcp, ~1ulp), head-mean (xor 16, 32)
  const float invd = 0.25f * __builtin_amdgcn_rcpf(d);
  const float inva[4] = {__builtin_amdgcn_rcpf(fabsf(avv.x)),
                         __builtin_amdgcn_rcpf(fabsf(avv.y)),
                         __builtin_amdgcn_rcpf(fabsf(avv.z)),
                         __builtin_amdgcn_rcpf(fabsf(avv.w))};
  float v[4];
#pragma unroll
  for (int q = 0; q < 4; q++) v[q] = acc[q] * invd * inva[q];
#pragma unroll
  for (int q = 0; q < 4; q++) {
    v[q] += __shfl_xor(v[q], 16);
    v[q] += __shfl_xor(v[q], 32);
  }
  if ((lane >> 4) == 0) {
    const float4 bq = *(const float4*)(bias + (lane & 15) * 4);
    const float bb[4] = {bq.x, bq.y, bq.z, bq.w};
    float o[4];
#pragma unroll
    for (int q = 0; q < 4; q++) {
      float x = v[q] + bb[q];
      o[q] = x > 0.f ? x : (__builtin_amdgcn_exp2f(x * LOG2E) - 1.f);  // elu
    }
    *(float4*)(out + (size_t)i * 64 + (lane & 15) * 4) = make_float4(o[0], o[1], o[2], o[3]);
  }
}

extern "C" void kernel_launch(void* const* d_in, const int* in_sizes, int n_in,
                              void* d_out, int out_size, void* d_ws, size_t ws_size,
                              hipStream_t stream) {
  const int* edge = (const int*)d_in[1];   // [2][E] : row0 = src, row1 = dst
  const float* emb = (const float*)d_in[2];
  const float* Wl = (const float*)d_in[3];
  const float* Wr = (const float*)d_in[4];
  const float* att = (const float*)d_in[5];
  const float* bias = (const float*)d_in[6];
  float* out = (float*)d_out;

  const int E = in_sizes[1] / 2;
  const int N = in_sizes[2] / D_IN;
  const int* src = edge;
  const int* dst = edge + E;

  // strictly disjoint carve; embh (gated) at the end
  const size_t NB = (size_t)N * 256 * 2;
  char* w = (char*)d_ws;
  bf16_t* xl = (bf16_t*)w;  w += NB;            // ail = |a|*xl (bf16)
  bf16_t* xr = (bf16_t*)w;  w += NB;            // air = |a|*xr (bf16)
  bf16_t* Wt = (bf16_t*)w;  w += (size_t)2 * 256 * 256 * 2;
  int* offs = (int*)w;      w += ((size_t)N + 64) * 4;
  int* deg = (int*)w;       w += ((size_t)N + 64) * 4;
  int* bsum = (int*)w;      w += 1024;
  int* rank = (int*)w;      w += (size_t)E * 4;
  int* csr = (int*)w;       w += (size_t)E * 4;
  bf16_t* embh = (bf16_t*)w;
  const size_t need_big = (size_t)(w - (char*)d_ws) + NB;
  const bool big = ws_size >= need_big;   // ws_size constant -> same path every call

  const int nb = (N + 1023) / 1024;
  const int zb = (N + 255) / 256;
  const int hb = (E + 255) / 256;
  const int n4 = big ? N * 64 : 0;            // conv work items /4
  const int cb = big ? (n4 + 255) / 256 : 0;  // conv blocks
  const int gb = ((N + 127) / 128) * 4;       // gemm blocks
  const int sb = hb;                          // scatter blocks

  // K0: zero deg  U  Wt convert
  hipLaunchKernelGGL(k_zero_wt, dim3(zb + 512), dim3(256), 0, stream, deg, N, zb, Wl, Wr, Wt);
  // K_A: hist(+rank)  U  emb->bf16 conv
  hipLaunchKernelGGL(k_hist_conv, dim3(hb + cb), dim3(256), 0, stream, dst, E, deg, rank, hb,
                     emb, embh, n4);
  // scan chain
  hipLaunchKernelGGL(k_scanA, dim3(nb), dim3(256), 0, stream, deg, offs, bsum, N);
  hipLaunchKernelGGL(k_scanB, dim3(1), dim3(128), 0, stream, bsum, offs, nb, E, N);
  hipLaunchKernelGGL(k_scanC, dim3(nb), dim3(256), 0, stream, offs, bsum, N);
  // K_E: gemm  U  scatter (independent work, overlapped)
  if (big) {
    hipLaunchKernelGGL(k_gemm_scatter<true>, dim3(gb + sb), dim3(256), 0, stream,
                       emb, embh, Wt, xl, xr, src, dst, offs, rank, csr, att, N, E, gb);
  } else {
    hipLaunchKernelGGL(k_gemm_scatter<false>, dim3(gb + sb), dim3(256), 0, stream,
                       emb, embh, Wt, xl, xr, src, dst, offs, rank, csr, att, N, E, gb);
  }
  // edge pass
  hipLaunchKernelGGL(k_edge, dim3((N + 3) / 4), dim3(256), 0, stream, xl, xr, offs, csr,
                     att, bias, out, N);
}

// Round 7
// 462.810 us; speedup vs baseline: 1.1250x; 1.0026x over previous
//
#include <hip/hip_runtime.h>
#include <hip/hip_bf16.h>
#include <stdint.h>

#define D_IN 256
#define NEG 0.2f
#define LOG2E 1.44269504f

typedef unsigned short bf16_t;
typedef __attribute__((ext_vector_type(8))) short bfrag;   // 8 bf16 = 4 VGPR
typedef __attribute__((ext_vector_type(4))) float ffrag;   // MFMA C/D
typedef int int4a __attribute__((ext_vector_type(4), aligned(4)));  // 4B-aligned int4

__device__ __forceinline__ bf16_t f2bf(float f) {
  unsigned int u = __float_as_uint(f);
  unsigned int r = u + 0x7FFFu + ((u >> 16) & 1u);   // RNE
  return (bf16_t)(r >> 16);
}
__device__ __forceinline__ unsigned int pk2(float a, float b) {
  return (unsigned int)f2bf(a) | ((unsigned int)f2bf(b) << 16);
}
// CDNA dot2: c += a0*b0 + a1*b1 (bf16 inputs, f32 accum) — verified assembles on gfx950 (R6)
__device__ __forceinline__ float dot2_bf16(unsigned a, unsigned b, float c) {
  float r;
  asm("v_dot2_f32_bf16 %0, %1, %2, %3" : "=v"(r) : "v"(a), "v"(b), "v"(c));
  return r;
}

// ---------------- K0: zero deg  UNION  Wt transpose+convert ----------------
__global__ __launch_bounds__(256) void k_zero_wt(int* __restrict__ deg, int n, int zb,
                                                 const float* __restrict__ Wl,
                                                 const float* __restrict__ Wr,
                                                 bf16_t* __restrict__ Wt) {
  const int b = blockIdx.x, tid = threadIdx.x;
  if (b < zb) {
    int i = b * 256 + tid;
    if (i < n) deg[i] = 0;
  } else {
    int gid = (b - zb) * 256 + tid;   // 2*256*256 total
    int w = gid >> 16;
    int c = (gid >> 8) & 255;
    int k = gid & 255;
    const float* W = w ? Wr : Wl;
    Wt[gid] = f2bf(W[k * 256 + c]);
  }
}

// ---------------- K_A: hist(+rank)  UNION  emb fp32->bf16 conv ----------------
__global__ __launch_bounds__(256) void k_hist_conv(const int* __restrict__ dst, int E,
                                                   int* __restrict__ deg, int* __restrict__ rank,
                                                   int hb,
                                                   const float* __restrict__ emb,
                                                   bf16_t* __restrict__ embh, int n4) {
  const int b = blockIdx.x, tid = threadIdx.x;
  if (b < hb) {
    int e = b * 256 + tid;
    if (e < E) rank[e] = atomicAdd(&deg[dst[e]], 1);
  } else {
    int i = (b - hb) * 256 + tid;
    if (i < n4) {
      float4 f = ((const float4*)emb)[i];
      uint2 o;
      o.x = pk2(f.x, f.y);
      o.y = pk2(f.z, f.w);
      ((uint2*)embh)[i] = o;
    }
  }
}

// ---------------- scan chain ----------------
__global__ __launch_bounds__(256) void k_scanA(const int* __restrict__ deg,
                                               int* __restrict__ offs,
                                               int* __restrict__ bsum, int N) {
  __shared__ int sh[256];
  int t = threadIdx.x;
  int base = blockIdx.x * 1024 + t * 4;
  int v[4];
#pragma unroll
  for (int q = 0; q < 4; q++) v[q] = (base + q < N) ? deg[base + q] : 0;
  int ls = v[0] + v[1] + v[2] + v[3];
  sh[t] = ls;
  __syncthreads();
  for (int ofs = 1; ofs < 256; ofs <<= 1) {
    int x = (t >= ofs) ? sh[t - ofs] : 0;
    __syncthreads();
    sh[t] += x;
    __syncthreads();
  }
  int run = sh[t] - ls;
#pragma unroll
  for (int q = 0; q < 4; q++) {
    if (base + q < N) offs[base + q] = run;
    run += v[q];
  }
  if (t == 255) bsum[blockIdx.x] = sh[255];
}

__global__ __launch_bounds__(128) void k_scanB(int* __restrict__ bsum, int* __restrict__ offs,
                                               int nb, int E, int N) {
  __shared__ int sh[128];
  int t = threadIdx.x;
  int v = (t < nb) ? bsum[t] : 0;
  sh[t] = v;
  __syncthreads();
  for (int ofs = 1; ofs < 128; ofs <<= 1) {
    int x = (t >= ofs) ? sh[t - ofs] : 0;
    __syncthreads();
    sh[t] += x;
    __syncthreads();
  }
  if (t < nb) bsum[t] = sh[t] - v;
  if (t == 0) offs[N] = E;
}

__global__ __launch_bounds__(256) void k_scanC(int* __restrict__ offs,
                                               const int* __restrict__ bsum, int N) {
  int t = threadIdx.x;
  int base = blockIdx.x * 1024 + t * 4;
  int add = bsum[blockIdx.x];
#pragma unroll
  for (int q = 0; q < 4; q++) {
    int i = base + q;
    if (i < N) offs[i] += add;
  }
}

// ---------------- K_E: MFMA GEMM  UNION  scatter (no atomic) ----------------
// gemm: 128x128 tile, BK=32, 4 waves x (64x64 via 4x4 MFMA 16x16x32)
// stores |a_c|-scaled bf16 (k_edge unscales at the end).
// XCD swizzle: co-locate the 4 sibling blocks (same A row-tile) on one XCD.
template <bool USEBF>
__global__ __launch_bounds__(256) void k_gemm_scatter(
    const float* __restrict__ emb, const bf16_t* __restrict__ embh,
    const bf16_t* __restrict__ Wt, bf16_t* __restrict__ xl, bf16_t* __restrict__ xr,
    const int* __restrict__ src, const int* __restrict__ dst,
    const int* __restrict__ offs, const int* __restrict__ rank, int* __restrict__ csr,
    const float* __restrict__ att,
    int N, int E, int gb) {
  __shared__ bf16_t As[128][40];
  __shared__ bf16_t Bs[128][40];
  const int tid = threadIdx.x;

  if ((int)blockIdx.x >= gb) {   // -------- scatter branch --------
    int e = ((int)blockIdx.x - gb) * 256 + tid;
    if (e < E) {
      int pos = offs[dst[e]] + rank[e];
      csr[pos] = src[e];
    }
    return;
  }

  // -------- gemm branch: bijective chunked XCD swizzle (8 XCDs) --------
  int g = (int)blockIdx.x;
  {
    int xcd = g & 7, slot = g >> 3;
    int q8 = gb >> 3, r8 = gb & 7;
    g = (xcd < r8 ? xcd * (q8 + 1) : r8 * (q8 + 1) + (xcd - r8) * q8) + slot;
  }
  const int bx = g >> 2, nt = g & 3;  // nt: 0,1->Wl; 2,3->Wr
  const int row0 = bx * 128;
  const bf16_t* Wp = Wt + (size_t)(nt >> 1) * 65536;
  bf16_t* dstp = (nt < 2) ? xl : xr;
  const int c0 = (nt & 1) * 128;

  const int wave = tid >> 6, lane = tid & 63;
  const int m0w = (wave & 1) * 64, n0w = (wave >> 1) * 64;
  const int fr = lane & 15;
  const int aq = (lane >> 4) * 8;

  const int srow = tid >> 1, sseg = (tid & 1) * 16;
  const int grow = row0 + srow;
  const bool aok = grow < N;
  const bf16_t* bp = Wp + (size_t)(c0 + srow) * 256 + sseg;

  ffrag acc[4][4];
#pragma unroll
  for (int mi = 0; mi < 4; mi++)
#pragma unroll
    for (int ni = 0; ni < 4; ni++) acc[mi][ni] = (ffrag)0.f;

  for (int k0 = 0; k0 < 256; k0 += 32) {
    uint4 pa0 = make_uint4(0, 0, 0, 0), pa1 = pa0;
    if (USEBF) {
      const bf16_t* ap = embh + (size_t)grow * 256 + sseg;
      if (aok) {
        pa0 = *(const uint4*)(ap + k0);
        pa1 = *(const uint4*)(ap + k0 + 8);
      }
    } else {
      const float* ap = emb + (size_t)grow * 256 + sseg;
      float4 f0 = make_float4(0, 0, 0, 0), f1 = f0, f2 = f0, f3 = f0;
      if (aok) {
        f0 = *(const float4*)(ap + k0);
        f1 = *(const float4*)(ap + k0 + 4);
        f2 = *(const float4*)(ap + k0 + 8);
        f3 = *(const float4*)(ap + k0 + 12);
      }
      pa0.x = pk2(f0.x, f0.y); pa0.y = pk2(f0.z, f0.w);
      pa0.z = pk2(f1.x, f1.y); pa0.w = pk2(f1.z, f1.w);
      pa1.x = pk2(f2.x, f2.y); pa1.y = pk2(f2.z, f2.w);
      pa1.z = pk2(f3.x, f3.y); pa1.w = pk2(f3.z, f3.w);
    }
    uint4 b0 = *(const uint4*)(bp + k0);
    uint4 b1 = *(const uint4*)(bp + k0 + 8);
    __syncthreads();
    *(uint4*)&As[srow][sseg] = pa0;
    *(uint4*)&As[srow][sseg + 8] = pa1;
    *(uint4*)&Bs[srow][sseg] = b0;
    *(uint4*)&Bs[srow][sseg + 8] = b1;
    __syncthreads();

    bfrag af[4], bfv[4];
#pragma unroll
    for (int mi = 0; mi < 4; mi++) af[mi] = *(const bfrag*)&As[m0w + mi * 16 + fr][aq];
#pragma unroll
    for (int ni = 0; ni < 4; ni++) bfv[ni] = *(const bfrag*)&Bs[n0w + ni * 16 + fr][aq];
#pragma unroll
    for (int mi = 0; mi < 4; mi++)
#pragma unroll
      for (int ni = 0; ni < 4; ni++)
        acc[mi][ni] = __builtin_amdgcn_mfma_f32_16x16x32_bf16(af[mi], bfv[ni], acc[mi][ni], 0, 0, 0);
  }

  const int rbase = m0w + (lane >> 4) * 4;

  // scaled bf16 store: ail/air = |a_c| * x_c  (k_edge unscales)
  float absa[4];
#pragma unroll
  for (int ni = 0; ni < 4; ni++) absa[ni] = fabsf(att[c0 + n0w + ni * 16 + fr]);
#pragma unroll
  for (int mi = 0; mi < 4; mi++) {
#pragma unroll
    for (int ni = 0; ni < 4; ni++) {
      int col = c0 + n0w + ni * 16 + fr;
#pragma unroll
      for (int rr = 0; rr < 4; rr++) {
        int row = row0 + rbase + mi * 16 + rr;
        if (row < N) dstp[(size_t)row * 256 + col] = f2bf(acc[mi][ni][rr] * absa[ni]);
      }
    }
  }
}

// ---------------- fused edge pass (R7: DPP reduce + dot2 linear term) ----------------
// one wave per dst node; lane = (head = lane>>4) x (4-ch group = lane&15), 4 ch/lane.
// stored ail=|a|*xl, air=|a|*xr (bf16). Identity:
//   score = 0.6*[ sgn.ail + (2/3) sgn.|ail+air| ] + 0.6*sgn.air
// pL = sgn.x via v_dot2_f32_bf16 (packed, verified on gfx950); pA = sgn.|t| via
// v_fma_f32 with free abs() modifier; p = fma(K,pA,pL). 16-lane reduce via DPP
// row_ror rotate-reduce (4 v_add_dpp, no ds_swizzle/lgkm waits).
// scores ~ N(0,0.04) -> plain exp2 overflow-safe.
__device__ __forceinline__ float wred16(float p) {
  int t;
  t = __builtin_amdgcn_update_dpp(0, __float_as_int(p), 0x128, 0xF, 0xF, false);  // row_ror:8
  p += __int_as_float(t);
  t = __builtin_amdgcn_update_dpp(0, __float_as_int(p), 0x124, 0xF, 0xF, false);  // row_ror:4
  p += __int_as_float(t);
  t = __builtin_amdgcn_update_dpp(0, __float_as_int(p), 0x122, 0xF, 0xF, false);  // row_ror:2
  p += __int_as_float(t);
  t = __builtin_amdgcn_update_dpp(0, __float_as_int(p), 0x121, 0xF, 0xF, false);  // row_ror:1
  p += __int_as_float(t);
  return p;
}

__global__ __launch_bounds__(256) void k_edge(const bf16_t* __restrict__ ail,
                                              const bf16_t* __restrict__ air,
                                              const int* __restrict__ offs,
                                              const int* __restrict__ csr,
                                              const float* __restrict__ att,
                                              const float* __restrict__ bias,
                                              float* __restrict__ out, int N) {
  const int wv = threadIdx.x >> 6;
  const int lane = threadIdx.x & 63;
  const int i = blockIdx.x * 4 + wv;
  if (i >= N) return;
  const int cbase = (lane >> 4) * 64 + (lane & 15) * 4;
  const unsigned cb2 = (unsigned)cbase * 2;   // byte offset within a 512B row
  const float K = 0.66666669f;        // 2/3
  const float C = 0.6f * LOG2E;       // folds the 0.6 scale + log2e into exp2 arg

  const float4 avv = *(const float4*)(att + cbase);
  const float sg[4] = {copysignf(1.f, avv.x), copysignf(1.f, avv.y),
                       copysignf(1.f, avv.z), copysignf(1.f, avv.w)};
  // packed bf16 signs for dot2 (+-1.0 exact in bf16)
  const unsigned sg01 = (avv.x < 0.f ? 0xBF80u : 0x3F80u) |
                        ((avv.y < 0.f ? 0xBF80u : 0x3F80u) << 16);
  const unsigned sg23 = (avv.z < 0.f ? 0xBF80u : 0x3F80u) |
                        ((avv.w < 0.f ? 0xBF80u : 0x3F80u) << 16);

  // xr row (keep packed + unpacked)
  const uint2 xru = *(const uint2*)((const char*)air + (((unsigned)i << 9) + cb2));
  float xrv[4];
  xrv[0] = __uint_as_float(xru.x << 16);
  xrv[1] = __uint_as_float(xru.x & 0xFFFF0000u);
  xrv[2] = __uint_as_float(xru.y << 16);
  xrv[3] = __uint_as_float(xru.y & 0xFFFF0000u);

  // per-node term: pre = C * sum_c sgn*air  (= 0.6*log2e * (a . xr_i))
  const float pre = C * wred16(dot2_bf16(sg01, xru.x, dot2_bf16(sg23, xru.y, 0.f)));

  // self loop
  float d, acc[4];
  {
    uint2 u = *(const uint2*)((const char*)ail + (((unsigned)i << 9) + cb2));
    float x[4];
    x[0] = __uint_as_float(u.x << 16);
    x[1] = __uint_as_float(u.x & 0xFFFF0000u);
    x[2] = __uint_as_float(u.y << 16);
    x[3] = __uint_as_float(u.y & 0xFFFF0000u);
    float pA = 0.f;
#pragma unroll
    for (int q = 0; q < 4; q++) pA = fmaf(sg[q], fabsf(x[q] + xrv[q]), pA);
    float pL = dot2_bf16(sg01, u.x, dot2_bf16(sg23, u.y, 0.f));
    float p = wred16(fmaf(K, pA, pL));
    float e = __builtin_amdgcn_exp2f(fmaf(C, p, pre));
    d = e;
#pragma unroll
    for (int q = 0; q < 4; q++) acc[q] = e * x[q];
  }

  int k = offs[i];
  const int kend = offs[i + 1];

  for (; k + 4 <= kend; k += 4) {
    const int4a j4 = *(const int4a*)(csr + k);
    uint2 u0 = *(const uint2*)((const char*)ail + (((unsigned)j4.x << 9) + cb2));
    uint2 u1 = *(const uint2*)((const char*)ail + (((unsigned)j4.y << 9) + cb2));
    uint2 u2 = *(const uint2*)((const char*)ail + (((unsigned)j4.z << 9) + cb2));
    uint2 u3 = *(const uint2*)((const char*)ail + (((unsigned)j4.w << 9) + cb2));

    float x0[4], x1[4], x2[4], x3[4];
    x0[0] = __uint_as_float(u0.x << 16); x0[1] = __uint_as_float(u0.x & 0xFFFF0000u);
    x0[2] = __uint_as_float(u0.y << 16); x0[3] = __uint_as_float(u0.y & 0xFFFF0000u);
    x1[0] = __uint_as_float(u1.x << 16); x1[1] = __uint_as_float(u1.x & 0xFFFF0000u);
    x1[2] = __uint_as_float(u1.y << 16); x1[3] = __uint_as_float(u1.y & 0xFFFF0000u);
    x2[0] = __uint_as_float(u2.x << 16); x2[1] = __uint_as_float(u2.x & 0xFFFF0000u);
    x2[2] = __uint_as_float(u2.y << 16); x2[3] = __uint_as_float(u2.y & 0xFFFF0000u);
    x3[0] = __uint_as_float(u3.x << 16); x3[1] = __uint_as_float(u3.x & 0xFFFF0000u);
    x3[2] = __uint_as_float(u3.y << 16); x3[3] = __uint_as_float(u3.y & 0xFFFF0000u);

    float pA0 = 0.f, pA1 = 0.f, pA2 = 0.f, pA3 = 0.f;
#pragma unroll
    for (int q = 0; q < 4; q++) {
      pA0 = fmaf(sg[q], fabsf(x0[q] + xrv[q]), pA0);
      pA1 = fmaf(sg[q], fabsf(x1[q] + xrv[q]), pA1);
      pA2 = fmaf(sg[q], fabsf(x2[q] + xrv[q]), pA2);
      pA3 = fmaf(sg[q], fabsf(x3[q] + xrv[q]), pA3);
    }
    float pL0 = dot2_bf16(sg01, u0.x, dot2_bf16(sg23, u0.y, 0.f));
    float pL1 = dot2_bf16(sg01, u1.x, dot2_bf16(sg23, u1.y, 0.f));
    float pL2 = dot2_bf16(sg01, u2.x, dot2_bf16(sg23, u2.y, 0.f));
    float pL3 = dot2_bf16(sg01, u3.x, dot2_bf16(sg23, u3.y, 0.f));

    float e0 = __builtin_amdgcn_exp2f(fmaf(C, wred16(fmaf(K, pA0, pL0)), pre));
    float e1 = __builtin_amdgcn_exp2f(fmaf(C, wred16(fmaf(K, pA1, pL1)), pre));
    float e2 = __builtin_amdgcn_exp2f(fmaf(C, wred16(fmaf(K, pA2, pL2)), pre));
    float e3 = __builtin_amdgcn_exp2f(fmaf(C, wred16(fmaf(K, pA3, pL3)), pre));
    d += (e0 + e1) + (e2 + e3);
#pragma unroll
    for (int q = 0; q < 4; q++) {
      acc[q] = fmaf(e0, x0[q], acc[q]);
      acc[q] = fmaf(e1, x1[q], acc[q]);
      acc[q] = fmaf(e2, x2[q], acc[q]);
      acc[q] = fmaf(e3, x3[q], acc[q]);
    }
  }
  for (; k < kend; ++k) {
    int j = csr[k];
    uint2 u = *(const uint2*)((const char*)ail + (((unsigned)j << 9) + cb2));
    float x[4];
    x[0] = __uint_as_float(u.x << 16);
    x[1] = __uint_as_float(u.x & 0xFFFF0000u);
    x[2] = __uint_as_float(u.y << 16);
    x[3] = __uint_as_float(u.y & 0xFFFF0000u);
    float pA = 0.f;
#pragma unroll
    for (int q = 0; q < 4; q++) pA = fmaf(sg[q], fabsf(x[q] + xrv[q]), pA);
    float pL = dot2_bf16(sg01, u.x, dot2_bf16(sg23, u.y, 0.f));
    float p = wred16(fmaf(K, pA, pL));
    float e = __builtin_amdgcn_exp2f(fmaf(C, p, pre));
    d += e;
#pragma unroll
    for (int q = 0; q < 4; q++) acc[q] = fmaf(e, x[q], acc[q]);
  }

  // per-head normalize, unscale by 1/|a_c| (v_rcp, ~1ulp), head-mean (xor 16, 32)
  const float invd = 0.25f * __builtin_amdgcn_rcpf(d);
  const float inva[4] = {__builtin_amdgcn_rcpf(fabsf(avv.x)),
                         __builtin_amdgcn_rcpf(fabsf(avv.y)),
                         __builtin_amdgcn_rcpf(fabsf(avv.z)),
                         __builtin_amdgcn_rcpf(fabsf(avv.w))};
  float v[4];
#pragma unroll
  for (int q = 0; q < 4; q++) v[q] = acc[q] * invd * inva[q];
#pragma unroll
  for (int q = 0; q < 4; q++) {
    v[q] += __shfl_xor(v[q], 16);
    v[q] += __shfl_xor(v[q], 32);
  }
  if ((lane >> 4) == 0) {
    const float4 bq = *(const float4*)(bias + (lane & 15) * 4);
    const float bb[4] = {bq.x, bq.y, bq.z, bq.w};
    float o[4];
#pragma unroll
    for (int q = 0; q < 4; q++) {
      float x = v[q] + bb[q];
      o[q] = x > 0.f ? x : (__builtin_amdgcn_exp2f(x * LOG2E) - 1.f);  // elu
    }
    *(float4*)(out + (size_t)i * 64 + (lane & 15) * 4) = make_float4(o[0], o[1], o[2], o[3]);
  }
}

extern "C" void kernel_launch(void* const* d_in, const int* in_sizes, int n_in,
                              void* d_out, int out_size, void* d_ws, size_t ws_size,
                              hipStream_t stream) {
  const int* edge = (const int*)d_in[1];   // [2][E] : row0 = src, row1 = dst
  const float* emb = (const float*)d_in[2];
  const float* Wl = (const float*)d_in[3];
  const float* Wr = (const float*)d_in[4];
  const float* att = (const float*)d_in[5];
  const float* bias = (const float*)d_in[6];
  float* out = (float*)d_out;

  const int E = in_sizes[1] / 2;
  const int N = in_sizes[2] / D_IN;
  const int* src = edge;
  const int* dst = edge + E;

  // strictly disjoint carve; embh (gated) at the end
  const size_t NB = (size_t)N * 256 * 2;
  char* w = (char*)d_ws;
  bf16_t* xl = (bf16_t*)w;  w += NB;            // ail = |a|*xl (bf16)
  bf16_t* xr = (bf16_t*)w;  w += NB;            // air = |a|*xr (bf16)
  bf16_t* Wt = (bf16_t*)w;  w += (size_t)2 * 256 * 256 * 2;
  int* offs = (int*)w;      w += ((size_t)N + 64) * 4;
  int* deg = (int*)w;       w += ((size_t)N + 64) * 4;
  int* bsum = (int*)w;      w += 1024;
  int* rank = (int*)w;      w += (size_t)E * 4;
  int* csr = (int*)w;       w += (size_t)E * 4;
  bf16_t* embh = (bf16_t*)w;
  const size_t need_big = (size_t)(w - (char*)d_ws) + NB;
  const bool big = ws_size >= need_big;   // ws_size constant -> same path every call

  const int nb = (N + 1023) / 1024;
  const int zb = (N + 255) / 256;
  const int hb = (E + 255) / 256;
  const int n4 = big ? N * 64 : 0;            // conv work items /4
  const int cb = big ? (n4 + 255) / 256 : 0;  // conv blocks
  const int gb = ((N + 127) / 128) * 4;       // gemm blocks
  const int sb = hb;                          // scatter blocks

  // K0: zero deg  U  Wt convert
  hipLaunchKernelGGL(k_zero_wt, dim3(zb + 512), dim3(256), 0, stream, deg, N, zb, Wl, Wr, Wt);
  // K_A: hist(+rank)  U  emb->bf16 conv
  hipLaunchKernelGGL(k_hist_conv, dim3(hb + cb), dim3(256), 0, stream, dst, E, deg, rank, hb,
                     emb, embh, n4);
  // scan chain
  hipLaunchKernelGGL(k_scanA, dim3(nb), dim3(256), 0, stream, deg, offs, bsum, N);
  hipLaunchKernelGGL(k_scanB, dim3(1), dim3(128), 0, stream, bsum, offs, nb, E, N);
  hipLaunchKernelGGL(k_scanC, dim3(nb), dim3(256), 0, stream, offs, bsum, N);
  // K_E: gemm  U  scatter (independent work, overlapped)
  if (big) {
    hipLaunchKernelGGL(k_gemm_scatter<true>, dim3(gb + sb), dim3(256), 0, stream,
                       emb, embh, Wt, xl, xr, src, dst, offs, rank, csr, att, N, E, gb);
  } else {
    hipLaunchKernelGGL(k_gemm_scatter<false>, dim3(gb + sb), dim3(256), 0, stream,
                       emb, embh, Wt, xl, xr, src, dst, offs, rank, csr, att, N, E, gb);
  }
  // edge pass
  hipLaunchKernelGGL(k_edge, dim3((N + 3) / 4), dim3(256), 0, stream, xl, xr, offs, csr,
                     att, bias, out, N);
}

// Round 8
// 462.474 us; speedup vs baseline: 1.1258x; 1.0007x over previous
//
#include <hip/hip_runtime.h>
#include <hip/hip_bf16.h>
#include <stdint.h>

#define D_IN 256
#define NEG 0.2f
#define LOG2E 1.44269504f

typedef unsigned short bf16_t;
typedef __attribute__((ext_vector_type(8))) short bfrag;   // 8 bf16 = 4 VGPR
typedef __attribute__((ext_vector_type(4))) float ffrag;   // MFMA C/D
typedef int int4a __attribute__((ext_vector_type(4), aligned(4)));  // 4B-aligned int4
typedef _Float16 h4 __attribute__((ext_vector_type(4)));   // 4 fp16 = 8B

__device__ __forceinline__ bf16_t f2bf(float f) {
  unsigned int u = __float_as_uint(f);
  unsigned int r = u + 0x7FFFu + ((u >> 16) & 1u);   // RNE
  return (bf16_t)(r >> 16);
}
__device__ __forceinline__ unsigned int pk2(float a, float b) {
  return (unsigned int)f2bf(a) | ((unsigned int)f2bf(b) << 16);
}
// CDNA dot2 f16: c += a0*b0 + a1*b1 (f16 inputs, f32 accum)
__device__ __forceinline__ float dot2_f16(unsigned a, unsigned b, float c) {
  float r;
  asm("v_dot2_f32_f16 %0, %1, %2, %3" : "=v"(r) : "v"(a), "v"(b), "v"(c));
  return r;
}
// packed f16 add (2 ch / inst) — gfx9-lineage VOP3P, present on CDNA
__device__ __forceinline__ unsigned pkadd_f16(unsigned a, unsigned b) {
  unsigned r;
  asm("v_pk_add_f16 %0, %1, %2" : "=v"(r) : "v"(a), "v"(b));
  return r;
}

// ---------------- K0: zero deg  UNION  Wt transpose+convert ----------------
__global__ __launch_bounds__(256) void k_zero_wt(int* __restrict__ deg, int n, int zb,
                                                 const float* __restrict__ Wl,
                                                 const float* __restrict__ Wr,
                                                 bf16_t* __restrict__ Wt) {
  const int b = blockIdx.x, tid = threadIdx.x;
  if (b < zb) {
    int i = b * 256 + tid;
    if (i < n) deg[i] = 0;
  } else {
    int gid = (b - zb) * 256 + tid;   // 2*256*256 total
    int w = gid >> 16;
    int c = (gid >> 8) & 255;
    int k = gid & 255;
    const float* W = w ? Wr : Wl;
    Wt[gid] = f2bf(W[k * 256 + c]);
  }
}

// ---------------- K_A: hist(+rank)  UNION  emb fp32->bf16 conv ----------------
__global__ __launch_bounds__(256) void k_hist_conv(const int* __restrict__ dst, int E,
                                                   int* __restrict__ deg, int* __restrict__ rank,
                                                   int hb,
                                                   const float* __restrict__ emb,
                                                   bf16_t* __restrict__ embh, int n4) {
  const int b = blockIdx.x, tid = threadIdx.x;
  if (b < hb) {
    int e = b * 256 + tid;
    if (e < E) rank[e] = atomicAdd(&deg[dst[e]], 1);
  } else {
    int i = (b - hb) * 256 + tid;
    if (i < n4) {
      float4 f = ((const float4*)emb)[i];
      uint2 o;
      o.x = pk2(f.x, f.y);
      o.y = pk2(f.z, f.w);
      ((uint2*)embh)[i] = o;
    }
  }
}

// ---------------- scan chain ----------------
__global__ __launch_bounds__(256) void k_scanA(const int* __restrict__ deg,
                                               int* __restrict__ offs,
                                               int* __restrict__ bsum, int N) {
  __shared__ int sh[256];
  int t = threadIdx.x;
  int base = blockIdx.x * 1024 + t * 4;
  int v[4];
#pragma unroll
  for (int q = 0; q < 4; q++) v[q] = (base + q < N) ? deg[base + q] : 0;
  int ls = v[0] + v[1] + v[2] + v[3];
  sh[t] = ls;
  __syncthreads();
  for (int ofs = 1; ofs < 256; ofs <<= 1) {
    int x = (t >= ofs) ? sh[t - ofs] : 0;
    __syncthreads();
    sh[t] += x;
    __syncthreads();
  }
  int run = sh[t] - ls;
#pragma unroll
  for (int q = 0; q < 4; q++) {
    if (base + q < N) offs[base + q] = run;
    run += v[q];
  }
  if (t == 255) bsum[blockIdx.x] = sh[255];
}

__global__ __launch_bounds__(128) void k_scanB(int* __restrict__ bsum, int* __restrict__ offs,
                                               int nb, int E, int N) {
  __shared__ int sh[128];
  int t = threadIdx.x;
  int v = (t < nb) ? bsum[t] : 0;
  sh[t] = v;
  __syncthreads();
  for (int ofs = 1; ofs < 128; ofs <<= 1) {
    int x = (t >= ofs) ? sh[t - ofs] : 0;
    __syncthreads();
    sh[t] += x;
    __syncthreads();
  }
  if (t < nb) bsum[t] = sh[t] - v;
  if (t == 0) offs[N] = E;
}

__global__ __launch_bounds__(256) void k_scanC(int* __restrict__ offs,
                                               const int* __restrict__ bsum, int N) {
  int t = threadIdx.x;
  int base = blockIdx.x * 1024 + t * 4;
  int add = bsum[blockIdx.x];
#pragma unroll
  for (int q = 0; q < 4; q++) {
    int i = base + q;
    if (i < N) offs[i] += add;
  }
}

// ---------------- K_E: MFMA GEMM  UNION  scatter (no atomic) ----------------
// gemm: 128x128 tile, BK=32, 4 waves x (64x64 via 4x4 MFMA 16x16x32)
// epilogue stores |a_c|-scaled **fp16** (k_edge unscales at the end).
// XCD swizzle: co-locate the 4 sibling blocks (same A row-tile) on one XCD.
template <bool USEBF>
__global__ __launch_bounds__(256) void k_gemm_scatter(
    const float* __restrict__ emb, const bf16_t* __restrict__ embh,
    const bf16_t* __restrict__ Wt, bf16_t* __restrict__ xl, bf16_t* __restrict__ xr,
    const int* __restrict__ src, const int* __restrict__ dst,
    const int* __restrict__ offs, const int* __restrict__ rank, int* __restrict__ csr,
    const float* __restrict__ att,
    int N, int E, int gb) {
  __shared__ bf16_t As[128][40];
  __shared__ bf16_t Bs[128][40];
  const int tid = threadIdx.x;

  if ((int)blockIdx.x >= gb) {   // -------- scatter branch --------
    int e = ((int)blockIdx.x - gb) * 256 + tid;
    if (e < E) {
      int pos = offs[dst[e]] + rank[e];
      csr[pos] = src[e];
    }
    return;
  }

  // -------- gemm branch: bijective chunked XCD swizzle (8 XCDs) --------
  int g = (int)blockIdx.x;
  {
    int xcd = g & 7, slot = g >> 3;
    int q8 = gb >> 3, r8 = gb & 7;
    g = (xcd < r8 ? xcd * (q8 + 1) : r8 * (q8 + 1) + (xcd - r8) * q8) + slot;
  }
  const int bx = g >> 2, nt = g & 3;  // nt: 0,1->Wl; 2,3->Wr
  const int row0 = bx * 128;
  const bf16_t* Wp = Wt + (size_t)(nt >> 1) * 65536;
  bf16_t* dstp = (nt < 2) ? xl : xr;
  const int c0 = (nt & 1) * 128;

  const int wave = tid >> 6, lane = tid & 63;
  const int m0w = (wave & 1) * 64, n0w = (wave >> 1) * 64;
  const int fr = lane & 15;
  const int aq = (lane >> 4) * 8;

  const int srow = tid >> 1, sseg = (tid & 1) * 16;
  const int grow = row0 + srow;
  const bool aok = grow < N;
  const bf16_t* bp = Wp + (size_t)(c0 + srow) * 256 + sseg;

  ffrag acc[4][4];
#pragma unroll
  for (int mi = 0; mi < 4; mi++)
#pragma unroll
    for (int ni = 0; ni < 4; ni++) acc[mi][ni] = (ffrag)0.f;

  for (int k0 = 0; k0 < 256; k0 += 32) {
    uint4 pa0 = make_uint4(0, 0, 0, 0), pa1 = pa0;
    if (USEBF) {
      const bf16_t* ap = embh + (size_t)grow * 256 + sseg;
      if (aok) {
        pa0 = *(const uint4*)(ap + k0);
        pa1 = *(const uint4*)(ap + k0 + 8);
      }
    } else {
      const float* ap = emb + (size_t)grow * 256 + sseg;
      float4 f0 = make_float4(0, 0, 0, 0), f1 = f0, f2 = f0, f3 = f0;
      if (aok) {
        f0 = *(const float4*)(ap + k0);
        f1 = *(const float4*)(ap + k0 + 4);
        f2 = *(const float4*)(ap + k0 + 8);
        f3 = *(const float4*)(ap + k0 + 12);
      }
      pa0.x = pk2(f0.x, f0.y); pa0.y = pk2(f0.z, f0.w);
      pa0.z = pk2(f1.x, f1.y); pa0.w = pk2(f1.z, f1.w);
      pa1.x = pk2(f2.x, f2.y); pa1.y = pk2(f2.z, f2.w);
      pa1.z = pk2(f3.x, f3.y); pa1.w = pk2(f3.z, f3.w);
    }
    uint4 b0 = *(const uint4*)(bp + k0);
    uint4 b1 = *(const uint4*)(bp + k0 + 8);
    __syncthreads();
    *(uint4*)&As[srow][sseg] = pa0;
    *(uint4*)&As[srow][sseg + 8] = pa1;
    *(uint4*)&Bs[srow][sseg] = b0;
    *(uint4*)&Bs[srow][sseg + 8] = b1;
    __syncthreads();

    bfrag af[4], bfv[4];
#pragma unroll
    for (int mi = 0; mi < 4; mi++) af[mi] = *(const bfrag*)&As[m0w + mi * 16 + fr][aq];
#pragma unroll
    for (int ni = 0; ni < 4; ni++) bfv[ni] = *(const bfrag*)&Bs[n0w + ni * 16 + fr][aq];
#pragma unroll
    for (int mi = 0; mi < 4; mi++)
#pragma unroll
      for (int ni = 0; ni < 4; ni++)
        acc[mi][ni] = __builtin_amdgcn_mfma_f32_16x16x32_bf16(af[mi], bfv[ni], acc[mi][ni], 0, 0, 0);
  }

  const int rbase = m0w + (lane >> 4) * 4;

  // scaled fp16 store: ail/air = |a_c| * x_c  (k_edge unscales)
  float absa[4];
#pragma unroll
  for (int ni = 0; ni < 4; ni++) absa[ni] = fabsf(att[c0 + n0w + ni * 16 + fr]);
#pragma unroll
  for (int mi = 0; mi < 4; mi++) {
#pragma unroll
    for (int ni = 0; ni < 4; ni++) {
      int col = c0 + n0w + ni * 16 + fr;
#pragma unroll
      for (int rr = 0; rr < 4; rr++) {
        int row = row0 + rbase + mi * 16 + rr;
        if (row < N)
          dstp[(size_t)row * 256 + col] =
              __builtin_bit_cast(unsigned short, (_Float16)(acc[mi][ni][rr] * absa[ni]));
      }
    }
  }
}

// ---------------- fused edge pass (R8: packed-fp16 score) ----------------
// one wave per dst node; lane = (head = lane>>4) x (4-ch group = lane&15), 4 ch/lane.
// staged ail=|a|*xl, air=|a|*xr as **fp16**. Identity:
//   score = 0.6*[ sgn.ail + (2/3) sgn.|ail+air| ] + 0.6*sgn.air
// Packed per edge (4 ch = 2 f16x2): 2 pk_add + 2 AND(|t|) + 4 dot2_f32_f16 + 1 fma.
// acc via (float)_Float16 casts (v_fma_mix_f32 folds the cvt). 16-lane reduce via
// DPP row_ror rotate-reduce. scores ~ N(0,0.04) -> plain exp2 overflow-safe.
__device__ __forceinline__ float wred16(float p) {
  int t;
  t = __builtin_amdgcn_update_dpp(0, __float_as_int(p), 0x128, 0xF, 0xF, false);  // row_ror:8
  p += __int_as_float(t);
  t = __builtin_amdgcn_update_dpp(0, __float_as_int(p), 0x124, 0xF, 0xF, false);  // row_ror:4
  p += __int_as_float(t);
  t = __builtin_amdgcn_update_dpp(0, __float_as_int(p), 0x122, 0xF, 0xF, false);  // row_ror:2
  p += __int_as_float(t);
  t = __builtin_amdgcn_update_dpp(0, __float_as_int(p), 0x121, 0xF, 0xF, false);  // row_ror:1
  p += __int_as_float(t);
  return p;
}

__global__ __launch_bounds__(256) void k_edge(const bf16_t* __restrict__ ail,
                                              const bf16_t* __restrict__ air,
                                              const int* __restrict__ offs,
                                              const int* __restrict__ csr,
                                              const float* __restrict__ att,
                                              const float* __restrict__ bias,
                                              float* __restrict__ out, int N) {
  const int wv = threadIdx.x >> 6;
  const int lane = threadIdx.x & 63;
  const int i = blockIdx.x * 4 + wv;
  if (i >= N) return;
  const int cbase = (lane >> 4) * 64 + (lane & 15) * 4;
  const unsigned cb2 = (unsigned)cbase * 2;   // byte offset within a 512B row
  const float K = 0.66666669f;        // 2/3
  const float C = 0.6f * LOG2E;       // folds the 0.6 scale + log2e into exp2 arg
  const unsigned ABSM = 0x7FFF7FFFu;

  const float4 avv = *(const float4*)(att + cbase);
  // packed f16 signs (+-1.0 exact: 0x3C00 / 0xBC00)
  const unsigned sg01 = (avv.x < 0.f ? 0xBC00u : 0x3C00u) |
                        ((avv.y < 0.f ? 0xBC00u : 0x3C00u) << 16);
  const unsigned sg23 = (avv.z < 0.f ? 0xBC00u : 0x3C00u) |
                        ((avv.w < 0.f ? 0xBC00u : 0x3C00u) << 16);

  // xr row (packed f16)
  const uint2 xru = *(const uint2*)((const char*)air + (((unsigned)i << 9) + cb2));

  // per-node term: pre = C * sum_c sgn*air  (= 0.6*log2e * (a . xr_i))
  const float pre = C * wred16(dot2_f16(sg01, xru.x, dot2_f16(sg23, xru.y, 0.f)));

  // self loop
  float d, acc[4];
  {
    uint2 u = *(const uint2*)((const char*)ail + (((unsigned)i << 9) + cb2));
    unsigned t0 = pkadd_f16(u.x, xru.x), t1 = pkadd_f16(u.y, xru.y);
    float pA = dot2_f16(sg01, t0 & ABSM, dot2_f16(sg23, t1 & ABSM, 0.f));
    float pL = dot2_f16(sg01, u.x, dot2_f16(sg23, u.y, 0.f));
    float p = wred16(fmaf(K, pA, pL));
    float e = __builtin_amdgcn_exp2f(fmaf(C, p, pre));
    d = e;
    h4 xh = __builtin_bit_cast(h4, u);
#pragma unroll
    for (int q = 0; q < 4; q++) acc[q] = e * (float)xh[q];
  }

  int k = offs[i];
  const int kend = offs[i + 1];

  for (; k + 4 <= kend; k += 4) {
    const int4a j4 = *(const int4a*)(csr + k);
    uint2 u0 = *(const uint2*)((const char*)ail + (((unsigned)j4.x << 9) + cb2));
    uint2 u1 = *(const uint2*)((const char*)ail + (((unsigned)j4.y << 9) + cb2));
    uint2 u2 = *(const uint2*)((const char*)ail + (((unsigned)j4.z << 9) + cb2));
    uint2 u3 = *(const uint2*)((const char*)ail + (((unsigned)j4.w << 9) + cb2));

    unsigned ta0 = pkadd_f16(u0.x, xru.x), tb0 = pkadd_f16(u0.y, xru.y);
    unsigned ta1 = pkadd_f16(u1.x, xru.x), tb1 = pkadd_f16(u1.y, xru.y);
    unsigned ta2 = pkadd_f16(u2.x, xru.x), tb2 = pkadd_f16(u2.y, xru.y);
    unsigned ta3 = pkadd_f16(u3.x, xru.x), tb3 = pkadd_f16(u3.y, xru.y);

    float pA0 = dot2_f16(sg01, ta0 & ABSM, dot2_f16(sg23, tb0 & ABSM, 0.f));
    float pA1 = dot2_f16(sg01, ta1 & ABSM, dot2_f16(sg23, tb1 & ABSM, 0.f));
    float pA2 = dot2_f16(sg01, ta2 & ABSM, dot2_f16(sg23, tb2 & ABSM, 0.f));
    float pA3 = dot2_f16(sg01, ta3 & ABSM, dot2_f16(sg23, tb3 & ABSM, 0.f));
    float pL0 = dot2_f16(sg01, u0.x, dot2_f16(sg23, u0.y, 0.f));
    float pL1 = dot2_f16(sg01, u1.x, dot2_f16(sg23, u1.y, 0.f));
    float pL2 = dot2_f16(sg01, u2.x, dot2_f16(sg23, u2.y, 0.f));
    float pL3 = dot2_f16(sg01, u3.x, dot2_f16(sg23, u3.y, 0.f));

    float e0 = __builtin_amdgcn_exp2f(fmaf(C, wred16(fmaf(K, pA0, pL0)), pre));
    float e1 = __builtin_amdgcn_exp2f(fmaf(C, wred16(fmaf(K, pA1, pL1)), pre));
    float e2 = __builtin_amdgcn_exp2f(fmaf(C, wred16(fmaf(K, pA2, pL2)), pre));
    float e3 = __builtin_amdgcn_exp2f(fmaf(C, wred16(fmaf(K, pA3, pL3)), pre));
    d += (e0 + e1) + (e2 + e3);

    h4 x0 = __builtin_bit_cast(h4, u0), x1 = __builtin_bit_cast(h4, u1);
    h4 x2 = __builtin_bit_cast(h4, u2), x3 = __builtin_bit_cast(h4, u3);
#pragma unroll
    for (int q = 0; q < 4; q++) {
      acc[q] = fmaf(e0, (float)x0[q], acc[q]);
      acc[q] = fmaf(e1, (float)x1[q], acc[q]);
      acc[q] = fmaf(e2, (float)x2[q], acc[q]);
      acc[q] = fmaf(e3, (float)x3[q], acc[q]);
    }
  }
  for (; k < kend; ++k) {
    int j = csr[k];
    uint2 u = *(const uint2*)((const char*)ail + (((unsigned)j << 9) + cb2));
    unsigned t0 = pkadd_f16(u.x, xru.x), t1 = pkadd_f16(u.y, xru.y);
    float pA = dot2_f16(sg01, t0 & ABSM, dot2_f16(sg23, t1 & ABSM, 0.f));
    float pL = dot2_f16(sg01, u.x, dot2_f16(sg23, u.y, 0.f));
    float p = wred16(fmaf(K, pA, pL));
    float e = __builtin_amdgcn_exp2f(fmaf(C, p, pre));
    d += e;
    h4 xh = __builtin_bit_cast(h4, u);
#pragma unroll
    for (int q = 0; q < 4; q++) acc[q] = fmaf(e, (float)xh[q], acc[q]);
  }

  // per-head normalize, unscale by 1/|a_c| (v_rcp, ~1ulp), head-mean (xor 16, 32)
  const float invd = 0.25f * __builtin_amdgcn_rcpf(d);
  const float inva[4] = {__builtin_amdgcn_rcpf(fabsf(avv.x)),
                         __builtin_amdgcn_rcpf(fabsf(avv.y)),
                         __builtin_amdgcn_rcpf(fabsf(avv.z)),
                         __builtin_amdgcn_rcpf(fabsf(avv.w))};
  float v[4];
#pragma unroll
  for (int q = 0; q < 4; q++) v[q] = acc[q] * invd * inva[q];
#pragma unroll
  for (int q = 0; q < 4; q++) {
    v[q] += __shfl_xor(v[q], 16);
    v[q] += __shfl_xor(v[q], 32);
  }
  if ((lane >> 4) == 0) {
    const float4 bq = *(const float4*)(bias + (lane & 15) * 4);
    const float bb[4] = {bq.x, bq.y, bq.z, bq.w};
    float o[4];
#pragma unroll
    for (int q = 0; q < 4; q++) {
      float x = v[q] + bb[q];
      o[q] = x > 0.f ? x : (__builtin_amdgcn_exp2f(x * LOG2E) - 1.f);  // elu
    }
    *(float4*)(out + (size_t)i * 64 + (lane & 15) * 4) = make_float4(o[0], o[1], o[2], o[3]);
  }
}

extern "C" void kernel_launch(void* const* d_in, const int* in_sizes, int n_in,
                              void* d_out, int out_size, void* d_ws, size_t ws_size,
                              hipStream_t stream) {
  const int* edge = (const int*)d_in[1];   // [2][E] : row0 = src, row1 = dst
  const float* emb = (const float*)d_in[2];
  const float* Wl = (const float*)d_in[3];
  const float* Wr = (const float*)d_in[4];
  const float* att = (const float*)d_in[5];
  const float* bias = (const float*)d_in[6];
  float* out = (float*)d_out;

  const int E = in_sizes[1] / 2;
  const int N = in_sizes[2] / D_IN;
  const int* src = edge;
  const int* dst = edge + E;

  // strictly disjoint carve; embh (gated) at the end
  const size_t NB = (size_t)N * 256 * 2;
  char* w = (char*)d_ws;
  bf16_t* xl = (bf16_t*)w;  w += NB;            // ail = |a|*xl (fp16)
  bf16_t* xr = (bf16_t*)w;  w += NB;            // air = |a|*xr (fp16)
  bf16_t* Wt = (bf16_t*)w;  w += (size_t)2 * 256 * 256 * 2;
  int* offs = (int*)w;      w += ((size_t)N + 64) * 4;
  int* deg = (int*)w;       w += ((size_t)N + 64) * 4;
  int* bsum = (int*)w;      w += 1024;
  int* rank = (int*)w;      w += (size_t)E * 4;
  int* csr = (int*)w;       w += (size_t)E * 4;
  bf16_t* embh = (bf16_t*)w;
  const size_t need_big = (size_t)(w - (char*)d_ws) + NB;
  const bool big = ws_size >= need_big;   // ws_size constant -> same path every call

  const int nb = (N + 1023) / 1024;
  const int zb = (N + 255) / 256;
  const int hb = (E + 255) / 256;
  const int n4 = big ? N * 64 : 0;            // conv work items /4
  const int cb = big ? (n4 + 255) / 256 : 0;  // conv blocks
  const int gb = ((N + 127) / 128) * 4;       // gemm blocks
  const int sb = hb;                          // scatter blocks

  // K0: zero deg  U  Wt convert
  hipLaunchKernelGGL(k_zero_wt, dim3(zb + 512), dim3(256), 0, stream, deg, N, zb, Wl, Wr, Wt);
  // K_A: hist(+rank)  U  emb->bf16 conv
  hipLaunchKernelGGL(k_hist_conv, dim3(hb + cb), dim3(256), 0, stream, dst, E, deg, rank, hb,
                     emb, embh, n4);
  // scan chain
  hipLaunchKernelGGL(k_scanA, dim3(nb), dim3(256), 0, stream, deg, offs, bsum, N);
  hipLaunchKernelGGL(k_scanB, dim3(1), dim3(128), 0, stream, bsum, offs, nb, E, N);
  hipLaunchKernelGGL(k_scanC, dim3(nb), dim3(256), 0, stream, offs, bsum, N);
  // K_E: gemm  U  scatter (independent work, overlapped)
  if (big) {
    hipLaunchKernelGGL(k_gemm_scatter<true>, dim3(gb + sb), dim3(256), 0, stream,
                       emb, embh, Wt, xl, xr, src, dst, offs, rank, csr, att, N, E, gb);
  } else {
    hipLaunchKernelGGL(k_gemm_scatter<false>, dim3(gb + sb), dim3(256), 0, stream,
                       emb, embh, Wt, xl, xr, src, dst, offs, rank, csr, att, N, E, gb);
  }
  // edge pass
  hipLaunchKernelGGL(k_edge, dim3((N + 3) / 4), dim3(256), 0, stream, xl, xr, offs, csr,
                     att, bias, out, N);
}